// Round 7
// baseline (978.249 us; speedup 1.0000x reference)
//
#include <hip/hip_runtime.h>
#include <hip/hip_bf16.h>
#include <cstdint>

typedef unsigned short u16;
typedef __bf16 bf16x8 __attribute__((ext_vector_type(8)));
typedef float f32x4 __attribute__((ext_vector_type(4)));
typedef float f32x8 __attribute__((ext_vector_type(8)));
typedef unsigned short u16x4 __attribute__((ext_vector_type(4)));
typedef unsigned short u16x8 __attribute__((ext_vector_type(8)));

#define BB 8
#define SS 512
#define NN 2048
#define HH 512
#define MM (BB*NN)   // 16384
#define NBLK 512

__device__ inline u16 f2b(float f) {
  __hip_bfloat16 h = __float2bfloat16(f);
  return *reinterpret_cast<u16*>(&h);
}
__device__ inline float b2f(u16 u) {
  unsigned x = ((unsigned)u) << 16;
  return __uint_as_float(x);
}
__device__ inline f32x8 b2f8(u16x8 v) {
  f32x8 r;
  #pragma unroll
  for (int k = 0; k < 8; ++k) r[k] = b2f(v[k]);
  return r;
}

#define GLOAD16(g, l) __builtin_amdgcn_global_load_lds( \
    (const __attribute__((address_space(1))) void*)(g), \
    (__attribute__((address_space(3))) void*)(l), 16, 0, 0)

// XCD-aware remap: 4 n-tiles of one m-tile run consecutively on one XCD (A-panel L2 reuse)
__device__ inline void remap_mn(int bid, int& m0, int& n0) {
  const int xcd = bid & 7, k = bid >> 3;   // 512 % 8 == 0 -> bijective
  m0 = (xcd * 16 + (k >> 2)) * 128;
  n0 = (k & 3) * 128;
}

// Software grid barrier: all NBLK blocks are co-resident by construction
// (launch_bounds(256,2) => VGPR<=256, LDS 33.5KB => capacity >= 2 blocks/CU => >= 512 total).
// Monotonic counter in ws, reset by an in-graph memset before each launch.
__device__ inline void gbar(unsigned* bar, unsigned target) {
  __syncthreads();
  if (threadIdx.x == 0) {
    __threadfence();   // agent-scope release (L2 writeback for cross-XCD visibility)
    __hip_atomic_fetch_add(bar, 1u, __ATOMIC_ACQ_REL, __HIP_MEMORY_SCOPE_AGENT);
    while (__hip_atomic_load(bar, __ATOMIC_ACQUIRE, __HIP_MEMORY_SCOPE_AGENT) < target)
      __builtin_amdgcn_s_sleep(2);
  }
  __syncthreads();
  __threadfence();     // acquire side for all waves (L1 invalidate)
}

__global__ __launch_bounds__(256, 2) void k_mega(
    const float* __restrict__ x, const float* __restrict__ W1, const float* __restrict__ b1,
    const float* __restrict__ W2, const float* __restrict__ b2,
    float* __restrict__ out, char* __restrict__ ws) {
  // ---- workspace layout ----
  float* fvp  = (float*)(ws + 0);            // 1 MB
  int*   meta = (int*)  (ws + 1048576);      // 1 KB
  int*   rowfl= (int*)  (ws + 1049600);      // 64 KB
  float* xs   = (float*)(ws + 1115136);      // 192 KB  [b][12][512]
  float* g1s  = (float*)(ws + 1311744);      // 192 KB  (contiguous after xs)
  float* V1   = (float*)(ws + 1508352);      // 512 KB  [b][32][512]
  float* V2   = (float*)(ws + 2032640);      // 512 KB
  float* rdt1 = (float*)(ws + 2556928);      // 1 KB
  float* rdt2 = (float*)(ws + 2557952);      // 1 KB
  u16*   w1b  = (u16*)  (ws + 2558976);      // 512 KB
  u16*   w2b  = (u16*)  (ws + 3083264);      // 512 KB
  float* w1t  = (float*)(ws + 3607552);      // 1 MB
  float* w2t  = (float*)(ws + 4656128);      // 1 MB
  unsigned* bar = (unsigned*)(ws + 5704704); // 1 KB (memset to 0 in-graph pre-launch)
  u16*   g1   = (u16*)  (ws + 5705728);      // 16 MB
  u16*   xr   = (u16*)  (ws + 22482944);     // 16 MB

  __shared__ __align__(16) char SM[33536];
  const int tid = threadIdx.x;

  // ================= P1: transpose x -> xr + fvp partials; weight prep; zero xs/g1s =================
  {
    float (*t)[33]  = (float(*)[33])SM;
    float (*ps)[32] = (float(*)[32])(SM + 4224);
    const int tx = tid & 31, ty = tid >> 5;
    for (int u = blockIdx.x; u < 8704; u += NBLK) {
      __syncthreads();
      if (u < 8192) {
        const int n0 = (u & 63) * 32, st = (u >> 6) & 15, b = u >> 10;
        const int s0 = st * 32;
        float acc = 0.f;
        for (int i = ty; i < 32; i += 8) {
          float w = x[(size_t)b*SS*NN + (size_t)(s0+i)*NN + (n0+tx)];
          t[i][tx] = w; acc += w;
        }
        ps[ty][tx] = acc;
        __syncthreads();
        if (ty == 0) {
          float s = 0.f;
          #pragma unroll
          for (int j = 0; j < 8; ++j) s += ps[j][tx];
          fvp[((size_t)(b*16 + st))*NN + n0 + tx] = s;
        }
        for (int i = ty; i < 32; i += 8)
          xr[((size_t)b*NN + (n0+i))*SS + (s0+tx)] = f2b(t[tx][i]);
      } else {
        const int b2v = u - 8192;
        const float* W = (b2v >> 8) ? W2 : W1;
        u16* wb   = (b2v >> 8) ? w2b : w1b;
        float* wt = (b2v >> 8) ? w2t : w1t;
        const int rem = b2v & 255;
        const int r0 = (rem >> 4) * 32, c0 = (rem & 15) * 32;
        for (int i = ty; i < 32; i += 8) {
          float vv = W[(size_t)(r0+i)*512 + c0 + tx];
          t[i][tx] = vv;
          wb[(size_t)(r0+i)*512 + c0 + tx] = f2b(vv);
        }
        __syncthreads();
        for (int i = ty; i < 32; i += 8)
          wt[(size_t)(c0+i)*512 + r0 + tx] = t[tx][i];   // wt[k][d] = W[d][k]
      }
    }
    const int gt = blockIdx.x * 256 + tid;
    if (gt < 24576) ((float4*)xs)[gt] = make_float4(0.f, 0.f, 0.f, 0.f);  // xs + g1s
  }
  gbar(bar, 1*NBLK);

  // ================= P2: topk+setsums (blocks 0..7) || classsums-xr (blocks 8..263) =================
  if (blockIdx.x < BB) {
    const int b = blockIdx.x;
    float* v = (float*)SM;                                   // 2048 f32
    unsigned long long* wk = (unsigned long long*)(SM + 8192);   // 8
    unsigned long long* winner = (unsigned long long*)(SM + 8256); // 2
    int* sel  = (int*)(SM + 8272);                           // 18
    int* scnt = (int*)(SM + 8352);                           // 12
    int* ccnt = (int*)(SM + 8400);                           // 12
    const int wv = tid >> 6, ln = tid & 63;

    float lv[8];
    {
      f32x4 a0 = {0,0,0,0}, a1 = {0,0,0,0};
      for (int sb_ = 0; sb_ < 16; ++sb_) {
        const f32x4* p = (const f32x4*)(fvp + ((size_t)(b*16 + sb_))*NN + tid*8);
        a0 += p[0]; a1 += p[1];
      }
      lv[0]=a0[0]; lv[1]=a0[1]; lv[2]=a0[2]; lv[3]=a0[3];
      lv[4]=a1[0]; lv[5]=a1[1]; lv[6]=a1[2]; lv[7]=a1[3];
    }
    #pragma unroll
    for (int j = 0; j < 8; ++j) v[tid*8+j] = lv[j];

    unsigned long long kD[8], kA[8];
    #pragma unroll
    for (int j = 0; j < 8; ++j) {
      unsigned u = __float_as_uint(lv[j]);
      u = (u & 0x80000000u) ? ~u : (u | 0x80000000u);
      unsigned idx = (unsigned)(tid*8 + j);
      kD[j] = ((unsigned long long)u << 32) | (0xFFFFFFFFu - idx);
      kA[j] = ((unsigned long long)(~u) << 32) | (0xFFFFFFFFu - idx);
    }
    unsigned mskD = 0, mskA = 0;
    for (int r = 0; r < 9; ++r) {
      unsigned long long bD = 0ull, bA = 0ull;
      #pragma unroll
      for (int j = 0; j < 8; ++j) {
        if (!((mskD >> j) & 1) && kD[j] > bD) bD = kD[j];
        if (!((mskA >> j) & 1) && kA[j] > bA) bA = kA[j];
      }
      #pragma unroll
      for (int o = 32; o > 0; o >>= 1) {
        unsigned long long oD = __shfl_xor(bD, o, 64);
        unsigned long long oA = __shfl_xor(bA, o, 64);
        if (oD > bD) bD = oD;
        if (oA > bA) bA = oA;
      }
      if (ln == 0) { wk[wv] = bD; wk[4+wv] = bA; }
      __syncthreads();
      if (tid == 0) {
        unsigned long long mD = wk[0], mA = wk[4];
        #pragma unroll
        for (int q = 1; q < 4; ++q) {
          if (wk[q] > mD) mD = wk[q];
          if (wk[4+q] > mA) mA = wk[4+q];
        }
        winner[0] = mD; winner[1] = mA;
        sel[r]   = (int)(0xFFFFFFFFu - (unsigned)mD);
        sel[9+r] = (int)(0xFFFFFFFFu - (unsigned)mA);
      }
      __syncthreads();
      unsigned iD = 0xFFFFFFFFu - (unsigned)winner[0];
      unsigned iA = 0xFFFFFFFFu - (unsigned)winner[1];
      if ((int)(iD >> 3) == tid) mskD |= 1u << (iD & 7);
      if ((int)(iA >> 3) == tid) mskA |= 1u << (iA & 7);
    }

    int cp = 0, cn = 0, cz = 0;
    #pragma unroll
    for (int j = 0; j < 8; ++j) { cp += (lv[j] > 0.f); cn += (lv[j] < 0.f); cz += (lv[j] == 0.f); }
    #pragma unroll
    for (int o = 32; o > 0; o >>= 1) { cp += __shfl_xor(cp, o, 64); cn += __shfl_xor(cn, o, 64); cz += __shfl_xor(cz, o, 64); }
    if (ln == 0) { ccnt[wv] = cp; ccnt[4+wv] = cn; ccnt[8+wv] = cz; }
    __syncthreads();
    if (tid == 0) {
      int CP = 0, CN = 0, CZ = 0;
      #pragma unroll
      for (int q = 0; q < 4; ++q) { CP += ccnt[q]; CN += ccnt[4+q]; CZ += ccnt[8+q]; }
      scnt[0] = CP; scnt[1] = CN; scnt[2] = CZ;
      for (int t2 = 3; t2 < 12; ++t2) scnt[t2] = 0;
      for (int r = 1; r < 9; ++r) {
        float wD = v[sel[r]];   scnt[3] += (wD > 0.f); scnt[4] += (wD < 0.f); scnt[5] += (wD == 0.f);
        float wA = v[sel[9+r]]; scnt[6] += (wA > 0.f); scnt[7] += (wA < 0.f); scnt[8] += (wA == 0.f);
        float wZ = v[r];        scnt[9] += (wZ > 0.f); scnt[10] += (wZ < 0.f); scnt[11] += (wZ == 0.f);
      }
    }
    __syncthreads();
    #pragma unroll
    for (int j = 0; j < 8; ++j) {
      const int i = tid*8 + j;
      float w = lv[j];
      int cls = (w > 0.f) ? 0 : ((w < 0.f) ? 1 : 2);
      int mD = 0, mA = 0;
      #pragma unroll
      for (int r = 1; r < 9; ++r) { mD |= (sel[r] == i); mA |= (sel[9+r] == i); }
      int mZ8 = (i >= 1 && i <= 8);
      rowfl[b*NN + i] = cls | (mD << 2) | (mA << 3) | (mZ8 << 4);
    }
    if (tid < 18) meta[b*32 + tid] = sel[tid];
    if (tid >= 18 && tid < 30) meta[b*32 + tid] = scnt[tid - 18];
    __syncthreads();
    // set sums of xr over D/A/Z8 rows (single-writer)
    #pragma unroll
    for (int half = 0; half < 2; ++half) {
      const int d = tid + half*256;
      float a[9];
      #pragma unroll
      for (int q = 0; q < 9; ++q) a[q] = 0.f;
      for (int r = 1; r < 9; ++r) {
        int iD = sel[r];   float wD = v[iD]; int cD = (wD>0.f)?0:((wD<0.f)?1:2);
        a[cD]   += b2f(xr[((size_t)b*NN + iD)*512 + d]);
        int iA = sel[9+r]; float wA = v[iA]; int cA = (wA>0.f)?0:((wA<0.f)?1:2);
        a[3+cA] += b2f(xr[((size_t)b*NN + iA)*512 + d]);
        float wZ = v[r];   int cZ = (wZ>0.f)?0:((wZ<0.f)?1:2);
        a[6+cZ] += b2f(xr[((size_t)b*NN + r)*512 + d]);
      }
      #pragma unroll
      for (int q = 0; q < 9; ++q) xs[((size_t)b*12 + 3 + q)*512 + d] = a[q];
    }
  } else if (blockIdx.x < 8 + 256) {
    const int u = blockIdx.x - 8, b = u >> 5, c = u & 31, n0 = c*64;
    f32x8* red = (f32x8*)SM;                 // [3][4][64]
    int* scls = (int*)(SM + 24576);          // 64
    if (tid < 64) {
      float s = 0.f;
      for (int sb_ = 0; sb_ < 16; ++sb_) s += fvp[((size_t)(b*16 + sb_))*NN + n0 + tid];
      scls[tid] = (s > 0.f) ? 0 : ((s < 0.f) ? 1 : 2);
    }
    __syncthreads();
    const int fc = tid & 63, rg = tid >> 6;
    f32x8 sp = {0,0,0,0,0,0,0,0}, sn = sp, sz = sp;
    for (int it = 0; it < 16; ++it) {
      const int nr = rg + it*4;
      const int cls = scls[nr];
      f32x8 hf = b2f8(*(const u16x8*)(xr + ((size_t)b*NN + n0 + nr)*512 + fc*8));
      if (cls == 0) sp += hf; else if (cls == 1) sn += hf; else sz += hf;
    }
    red[(0*4+rg)*64+fc] = sp; red[(1*4+rg)*64+fc] = sn; red[(2*4+rg)*64+fc] = sz;
    __syncthreads();
    if (rg == 0) {
      sp = red[0*64+fc] + red[1*64+fc] + red[2*64+fc] + red[3*64+fc];
      sn = red[(4+0)*64+fc] + red[(4+1)*64+fc] + red[(4+2)*64+fc] + red[(4+3)*64+fc];
      sz = red[(8+0)*64+fc] + red[(8+1)*64+fc] + red[(8+2)*64+fc] + red[(8+3)*64+fc];
      #pragma unroll
      for (int j = 0; j < 8; ++j) {
        atomicAdd(&xs[((size_t)b*12 + 0)*512 + fc*8 + j], sp[j]);
        atomicAdd(&xs[((size_t)b*12 + 1)*512 + fc*8 + j], sn[j]);
        atomicAdd(&xs[((size_t)b*12 + 2)*512 + fc*8 + j], sz[j]);
      }
    }
  }
  gbar(bar, 2*NBLK);

  // ================= P3: sgemm -> V1, rdt1 =================
  if (blockIdx.x < 32) {
    const int u = blockIdx.x, b = u >> 2, d0 = (u & 3) * 128;
    float* xsl = (float*)SM;               // 12*512
    float* slv = (float*)(SM + 24576);     // 12*128
    int* cnt   = (int*)(SM + 30720);       // 12
    for (int i = tid; i < 12*512; i += 256) xsl[i] = xs[(size_t)b*12*HH + i];
    if (tid < 12) cnt[tid] = meta[b*32 + 18 + tid];
    __syncthreads();
    const int dl = tid & 127, vg = tid >> 7;
    const int d = d0 + dl, v0 = vg * 6;
    float a[6] = {0,0,0,0,0,0};
    for (int k = 0; k < 512; ++k) {
      float wv = w1t[(size_t)k*512 + d];
      #pragma unroll
      for (int q = 0; q < 6; ++q) a[q] += xsl[(v0+q)*512 + k] * wv;
    }
    float bv = b1[d];
    #pragma unroll
    for (int q = 0; q < 6; ++q) slv[(v0+q)*128 + dl] = a[q] + (float)cnt[v0+q] * bv;
    __syncthreads();
    for (int q = 0; q < 16; ++q) {
      int item = tid + q*256;
      int fl = item >> 7, dl2 = item & 127;
      int cls = fl & 3; if (cls == 3) cls = 2;
      int mD = (fl >> 2) & 1, mA = (fl >> 3) & 1, mZ = (fl >> 4) & 1;
      float c3 = mD*slv[0*128+dl2] + mA*slv[1*128+dl2] + mZ*slv[2*128+dl2];
      float c3c = (float)(mD*cnt[0] + mA*cnt[1] + mZ*cnt[2]);
      int rb = 3 + cls*3;
      float c2s = slv[rb*128+dl2] + slv[(rb+1)*128+dl2] + slv[(rb+2)*128+dl2]
                - mD*slv[rb*128+dl2] - mA*slv[(rb+1)*128+dl2] - mZ*slv[(rb+2)*128+dl2];
      float c2c = (float)(cnt[rb] + cnt[rb+1] + cnt[rb+2]
                - mD*cnt[rb] - mA*cnt[rb+1] - mZ*cnt[rb+2]);
      bool cself = (cls == 0 && mD) || (cls == 1 && mA) || (cls == 2 && mZ);
      float deg = c3c + c2c + (cself ? 0.f : 1.f);
      if (deg < 1.f) deg = 1.f;
      V1[((size_t)(b*32 + fl))*512 + d0 + dl2] = (c3 + c2s) / deg;
    }
    if ((u & 3) == 0 && tid < 32) {
      int fl = tid;
      int cls = fl & 3; if (cls == 3) cls = 2;
      int mD = (fl >> 2) & 1, mA = (fl >> 3) & 1, mZ = (fl >> 4) & 1;
      float c3c = (float)(mD*cnt[0] + mA*cnt[1] + mZ*cnt[2]);
      int rb = 3 + cls*3;
      float c2c = (float)(cnt[rb] + cnt[rb+1] + cnt[rb+2]
                - mD*cnt[rb] - mA*cnt[rb+1] - mZ*cnt[rb+2]);
      bool cself = (cls == 0 && mD) || (cls == 1 && mA) || (cls == 2 && mZ);
      float deg = c3c + c2c + (cself ? 0.f : 1.f);
      if (deg < 1.f) deg = 1.f;
      rdt1[b*32 + fl] = 1.f / deg;
    }
  }
  gbar(bar, 3*NBLK);

  // ================= P4: gemm1 fused -> g1 bf16 =================
  {
    u16* As = (u16*)SM;
    u16* Bs = (u16*)(SM + 8192);
    const int w = tid >> 6, l = tid & 63;
    const int wm = w >> 1, wn = w & 1;
    int m0, n0; remap_mn(blockIdx.x, m0, n0);
    const int b = m0 >> 11;
    f32x4 acc[4][4];
    #pragma unroll
    for (int i = 0; i < 4; ++i)
      #pragma unroll
      for (int j = 0; j < 4; ++j) acc[i][j] = (f32x4){0.f, 0.f, 0.f, 0.f};
    const int srow = l >> 2, skk = (l & 3) * 8;
    for (int kt = 0; kt < 512; kt += 32) {
      #pragma unroll
      for (int p = 0; p < 2; ++p) {
        const int q = w*2 + p;
        GLOAD16(xr  + (size_t)(m0 + q*16 + srow)*512 + kt + skk, As + q*512);
        GLOAD16(w1b + (size_t)(n0 + q*16 + srow)*512 + kt + skk, Bs + q*512);
      }
      __syncthreads();
      bf16x8 af[4], bfr[4];
      const int lr = l & 15, lk = (l >> 4) * 8;
      #pragma unroll
      for (int i = 0; i < 4; ++i) af[i] = *(const bf16x8*)(As + (wm*64 + i*16 + lr)*32 + lk);
      #pragma unroll
      for (int j = 0; j < 4; ++j) bfr[j] = *(const bf16x8*)(Bs + (wn*64 + j*16 + lr)*32 + lk);
      #pragma unroll
      for (int i = 0; i < 4; ++i)
        #pragma unroll
        for (int j = 0; j < 4; ++j)
          acc[i][j] = __builtin_amdgcn_mfma_f32_16x16x32_bf16(bfr[j], af[i], acc[i][j], 0, 0, 0);
      __syncthreads();
    }
    const int lr = l & 15;
    int fl[4]; float rd[4]; bool cs[4];
    #pragma unroll
    for (int i = 0; i < 4; ++i) {
      const int m = m0 + wm*64 + i*16 + lr;
      fl[i] = rowfl[m];
      rd[i] = rdt1[b*32 + fl[i]];
      const int cls = fl[i] & 3;
      cs[i] = (cls == 0 && (fl[i]&4)) || (cls == 1 && (fl[i]&8)) || (cls == 2 && (fl[i]&16));
    }
    #pragma unroll
    for (int j = 0; j < 4; ++j) {
      const int dg = n0 + wn*64 + j*16 + (l >> 4)*4;
      const f32x4 bi4 = *(const f32x4*)(b1 + dg);
      #pragma unroll
      for (int i = 0; i < 4; ++i) {
        const int m = m0 + wm*64 + i*16 + lr;
        f32x4 val = *(const f32x4*)(V1 + ((size_t)(b*32 + fl[i]))*512 + dg);
        if (!cs[i]) val += (acc[i][j] + bi4) * rd[i];
        u16x4 o;
        #pragma unroll
        for (int r = 0; r < 4; ++r) o[r] = f2b(fmaxf(val[r], 0.f));
        *(u16x4*)(g1 + (size_t)m*512 + dg) = o;
      }
    }
  }
  gbar(bar, 4*NBLK);

  // ================= P5: g1 sums (setsums blocks 0..7 || classsums 8..263) =================
  if (blockIdx.x < BB) {
    const int b = blockIdx.x;
    const int* mb = meta + b*32;
    #pragma unroll
    for (int half = 0; half < 2; ++half) {
      const int d = tid + half*256;
      float a[9];
      #pragma unroll
      for (int q = 0; q < 9; ++q) a[q] = 0.f;
      for (int r = 1; r < 9; ++r) {
        int iD = mb[r];   int cD = rowfl[b*NN + iD] & 3;
        a[cD]   += b2f(g1[((size_t)b*NN + iD)*512 + d]);
        int iA = mb[9+r]; int cA = rowfl[b*NN + iA] & 3;
        a[3+cA] += b2f(g1[((size_t)b*NN + iA)*512 + d]);
        int cZ = rowfl[b*NN + r] & 3;
        a[6+cZ] += b2f(g1[((size_t)b*NN + r)*512 + d]);
      }
      #pragma unroll
      for (int q = 0; q < 9; ++q) g1s[((size_t)b*12 + 3 + q)*512 + d] = a[q];
    }
  } else if (blockIdx.x < 8 + 256) {
    const int u = blockIdx.x - 8, b = u >> 5, c = u & 31, n0 = c*64;
    f32x8* red = (f32x8*)SM;
    int* scls = (int*)(SM + 24576);
    if (tid < 64) scls[tid] = rowfl[b*NN + n0 + tid] & 3;
    __syncthreads();
    const int fc = tid & 63, rg = tid >> 6;
    f32x8 sp = {0,0,0,0,0,0,0,0}, sn = sp, sz = sp;
    for (int it = 0; it < 16; ++it) {
      const int nr = rg + it*4;
      const int cls = scls[nr];
      f32x8 hf = b2f8(*(const u16x8*)(g1 + ((size_t)b*NN + n0 + nr)*512 + fc*8));
      if (cls == 0) sp += hf; else if (cls == 1) sn += hf; else sz += hf;
    }
    red[(0*4+rg)*64+fc] = sp; red[(1*4+rg)*64+fc] = sn; red[(2*4+rg)*64+fc] = sz;
    __syncthreads();
    if (rg == 0) {
      sp = red[0*64+fc] + red[1*64+fc] + red[2*64+fc] + red[3*64+fc];
      sn = red[(4+0)*64+fc] + red[(4+1)*64+fc] + red[(4+2)*64+fc] + red[(4+3)*64+fc];
      sz = red[(8+0)*64+fc] + red[(8+1)*64+fc] + red[(8+2)*64+fc] + red[(8+3)*64+fc];
      #pragma unroll
      for (int j = 0; j < 8; ++j) {
        atomicAdd(&g1s[((size_t)b*12 + 0)*512 + fc*8 + j], sp[j]);
        atomicAdd(&g1s[((size_t)b*12 + 1)*512 + fc*8 + j], sn[j]);
        atomicAdd(&g1s[((size_t)b*12 + 2)*512 + fc*8 + j], sz[j]);
      }
    }
  }
  gbar(bar, 5*NBLK);

  // ================= P6: sgemm -> V2, rdt2 =================
  if (blockIdx.x < 32) {
    const int u = blockIdx.x, b = u >> 2, d0 = (u & 3) * 128;
    float* xsl = (float*)SM;
    float* slv = (float*)(SM + 24576);
    int* cnt   = (int*)(SM + 30720);
    for (int i = tid; i < 12*512; i += 256) xsl[i] = g1s[(size_t)b*12*HH + i];
    if (tid < 12) cnt[tid] = meta[b*32 + 18 + tid];
    __syncthreads();
    const int dl = tid & 127, vg = tid >> 7;
    const int d = d0 + dl, v0 = vg * 6;
    float a[6] = {0,0,0,0,0,0};
    for (int k = 0; k < 512; ++k) {
      float wv = w2t[(size_t)k*512 + d];
      #pragma unroll
      for (int q = 0; q < 6; ++q) a[q] += xsl[(v0+q)*512 + k] * wv;
    }
    float bv = b2[d];
    #pragma unroll
    for (int q = 0; q < 6; ++q) slv[(v0+q)*128 + dl] = a[q] + (float)cnt[v0+q] * bv;
    __syncthreads();
    for (int q = 0; q < 16; ++q) {
      int item = tid + q*256;
      int fl = item >> 7, dl2 = item & 127;
      int cls = fl & 3; if (cls == 3) cls = 2;
      int mD = (fl >> 2) & 1, mA = (fl >> 3) & 1, mZ = (fl >> 4) & 1;
      float c3 = mD*slv[0*128+dl2] + mA*slv[1*128+dl2] + mZ*slv[2*128+dl2];
      float c3c = (float)(mD*cnt[0] + mA*cnt[1] + mZ*cnt[2]);
      int rb = 3 + cls*3;
      float c2s = slv[rb*128+dl2] + slv[(rb+1)*128+dl2] + slv[(rb+2)*128+dl2]
                - mD*slv[rb*128+dl2] - mA*slv[(rb+1)*128+dl2] - mZ*slv[(rb+2)*128+dl2];
      float c2c = (float)(cnt[rb] + cnt[rb+1] + cnt[rb+2]
                - mD*cnt[rb] - mA*cnt[rb+1] - mZ*cnt[rb+2]);
      bool cself = (cls == 0 && mD) || (cls == 1 && mA) || (cls == 2 && mZ);
      float deg = c3c + c2c + (cself ? 0.f : 1.f);
      if (deg < 1.f) deg = 1.f;
      V2[((size_t)(b*32 + fl))*512 + d0 + dl2] = (c3 + c2s) / deg;
    }
    if ((u & 3) == 0 && tid < 32) {
      int fl = tid;
      int cls = fl & 3; if (cls == 3) cls = 2;
      int mD = (fl >> 2) & 1, mA = (fl >> 3) & 1, mZ = (fl >> 4) & 1;
      float c3c = (float)(mD*cnt[0] + mA*cnt[1] + mZ*cnt[2]);
      int rb = 3 + cls*3;
      float c2c = (float)(cnt[rb] + cnt[rb+1] + cnt[rb+2]
                - mD*cnt[rb] - mA*cnt[rb+1] - mZ*cnt[rb+2]);
      bool cself = (cls == 0 && mD) || (cls == 1 && mA) || (cls == 2 && mZ);
      float deg = c3c + c2c + (cself ? 0.f : 1.f);
      if (deg < 1.f) deg = 1.f;
      rdt2[b*32 + fl] = 1.f / deg;
    }
  }
  gbar(bar, 6*NBLK);

  // ================= P7: gemm2 fused + transpose -> out (B,S,N) f32 =================
  {
    u16* As = (u16*)SM;
    u16* Bs = (u16*)(SM + 8192);
    const int w = tid >> 6, l = tid & 63;
    const int wm = w >> 1, wn = w & 1;
    int m0, n0; remap_mn(blockIdx.x, m0, n0);
    const int b = m0 >> 11;
    f32x4 acc[4][4];
    #pragma unroll
    for (int i = 0; i < 4; ++i)
      #pragma unroll
      for (int j = 0; j < 4; ++j) acc[i][j] = (f32x4){0.f, 0.f, 0.f, 0.f};
    const int srow = l >> 2, skk = (l & 3) * 8;
    for (int kt = 0; kt < 512; kt += 32) {
      #pragma unroll
      for (int p = 0; p < 2; ++p) {
        const int q = w*2 + p;
        GLOAD16(g1  + (size_t)(m0 + q*16 + srow)*512 + kt + skk, As + q*512);
        GLOAD16(w2b + (size_t)(n0 + q*16 + srow)*512 + kt + skk, Bs + q*512);
      }
      __syncthreads();
      bf16x8 af[4], bfr[4];
      const int lr = l & 15, lk = (l >> 4) * 8;
      #pragma unroll
      for (int i = 0; i < 4; ++i) af[i] = *(const bf16x8*)(As + (wm*64 + i*16 + lr)*32 + lk);
      #pragma unroll
      for (int j = 0; j < 4; ++j) bfr[j] = *(const bf16x8*)(Bs + (wn*64 + j*16 + lr)*32 + lk);
      #pragma unroll
      for (int i = 0; i < 4; ++i)
        #pragma unroll
        for (int j = 0; j < 4; ++j)
          acc[i][j] = __builtin_amdgcn_mfma_f32_16x16x32_bf16(bfr[j], af[i], acc[i][j], 0, 0, 0);
      __syncthreads();
    }
    float (*ep)[130] = (float(*)[130])SM;   // reuse As/Bs region (33280 B)
    const int lr = l & 15;
    int fl[4]; float rd[4]; bool cs[4];
    #pragma unroll
    for (int i = 0; i < 4; ++i) {
      const int m = m0 + wm*64 + i*16 + lr;
      fl[i] = rowfl[m];
      rd[i] = rdt2[b*32 + fl[i]];
      const int cls = fl[i] & 3;
      cs[i] = (cls == 0 && (fl[i]&4)) || (cls == 1 && (fl[i]&8)) || (cls == 2 && (fl[i]&16));
    }
    const int nloc = m0 & 2047;
    #pragma unroll
    for (int p = 0; p < 2; ++p) {
      #pragma unroll
      for (int jj = 0; jj < 2; ++jj) {
        const int j = 2*p + jj;
        const int dg = n0 + wn*64 + j*16 + (l >> 4)*4;
        const int dc = wn*32 + jj*16 + (l >> 4)*4;
        const f32x4 bi4 = *(const f32x4*)(b2 + dg);
        #pragma unroll
        for (int i = 0; i < 4; ++i) {
          const int mloc = wm*64 + i*16 + lr;
          f32x4 val = *(const f32x4*)(V2 + ((size_t)(b*32 + fl[i]))*512 + dg);
          if (!cs[i]) val += (acc[i][j] + bi4) * rd[i];
          #pragma unroll
          for (int r = 0; r < 4; ++r) ep[dc + r][mloc] = val[r];
        }
      }
      __syncthreads();
      for (int rr = 0; rr < 16; ++rr) {
        const int dc = w*16 + rr;
        const int wnn = dc >> 5, jj2 = (dc >> 4) & 1, within = dc & 15;
        const int s = n0 + wnn*64 + (2*p + jj2)*16 + within;
        float2 v2 = *(const float2*)&ep[dc][2*l];
        *(float2*)(out + ((size_t)b*SS + s)*NN + nloc + 2*l) = v2;
      }
      __syncthreads();
    }
  }
}

extern "C" void kernel_launch(void* const* d_in, const int* in_sizes, int n_in,
                              void* d_out, int out_size, void* d_ws, size_t ws_size,
                              hipStream_t stream) {
  const float* x  = (const float*)d_in[0];
  const float* W1 = (const float*)d_in[1];
  const float* b1 = (const float*)d_in[2];
  const float* W2 = (const float*)d_in[3];
  const float* b2 = (const float*)d_in[4];
  float* out = (float*)d_out;
  char* ws = (char*)d_ws;

  // reset the software grid barrier (in-graph node, runs before the kernel each replay)
  hipMemsetAsync(ws + 5704704, 0, 1024, stream);
  k_mega<<<NBLK, 256, 0, stream>>>(x, W1, b1, W2, b2, out, ws);
}

// Round 9
// 166.079 us; speedup vs baseline: 5.8903x; 5.8903x over previous
//
#include <hip/hip_runtime.h>
#include <hip/hip_bf16.h>
#include <cstdint>

typedef unsigned short u16;
typedef __bf16 bf16x8 __attribute__((ext_vector_type(8)));
typedef float f32x4 __attribute__((ext_vector_type(4)));
typedef float f32x8 __attribute__((ext_vector_type(8)));
typedef unsigned short u16x4 __attribute__((ext_vector_type(4)));
typedef unsigned short u16x8 __attribute__((ext_vector_type(8)));

#define BB 8
#define SS 512
#define NN 2048
#define HH 512
#define MM (BB*NN)   // 16384

__device__ inline u16 f2b(float f) {
  __hip_bfloat16 h = __float2bfloat16(f);
  return *reinterpret_cast<u16*>(&h);
}
__device__ inline float b2f(u16 u) {
  unsigned x = ((unsigned)u) << 16;
  return __uint_as_float(x);
}
__device__ inline f32x8 b2f8(u16x8 v) {
  f32x8 r;
  #pragma unroll
  for (int k = 0; k < 8; ++k) r[k] = b2f(v[k]);
  return r;
}

#define GLOAD16(g, l) __builtin_amdgcn_global_load_lds( \
    (const __attribute__((address_space(1))) void*)(g), \
    (__attribute__((address_space(3))) void*)(l), 16, 0, 0)

// XCD-aware remap: 4 n-tiles of one m-tile run consecutively on one XCD (A-panel L2 reuse)
__device__ inline void remap_mn(int bid, int& m0, int& n0) {
  const int xcd = bid & 7, k = bid >> 3;   // 512 % 8 == 0 -> bijective
  m0 = (xcd * 16 + (k >> 2)) * 128;
  n0 = (k & 3) * 128;
}

// ---------- P1: transpose x -> xr bf16 + fvp partials; weight bf16 cast; zero xs/g1s bins ----------
__global__ __launch_bounds__(256) void k_prep(const float* __restrict__ x, u16* __restrict__ xr,
                       float* __restrict__ fvp,
                       const float* __restrict__ W1, const float* __restrict__ W2,
                       u16* __restrict__ w1b, u16* __restrict__ w2b,
                       float* __restrict__ xs /* xs+g1s contiguous */) {
  __shared__ float t[32][33];
  __shared__ float ps[8][32];
  const int u = blockIdx.x;
  const int tx = threadIdx.x, ty = threadIdx.y;
  const int tid = ty*32 + tx;
  if (u < 8192) {
    const int n0 = (u & 63) * 32, st = (u >> 6) & 15, b = u >> 10;
    const int s0 = st * 32;
    float acc = 0.f;
    for (int i = ty; i < 32; i += 8) {
      float w = x[(size_t)b*SS*NN + (size_t)(s0+i)*NN + (n0+tx)];
      t[i][tx] = w; acc += w;
    }
    ps[ty][tx] = acc;
    __syncthreads();
    if (ty == 0) {
      float s = 0.f;
      #pragma unroll
      for (int j = 0; j < 8; ++j) s += ps[j][tx];
      fvp[((size_t)(b*16 + st))*NN + n0 + tx] = s;
    }
    for (int i = ty; i < 32; i += 8)
      xr[((size_t)b*NN + (n0+i))*SS + (s0+tx)] = f2b(t[tx][i]);
    if (u < 96) {   // zero xs + g1s (2 * 8*12*512 f32 = 24576 float4)
      ((float4*)xs)[u*256 + tid] = make_float4(0.f, 0.f, 0.f, 0.f);
    }
  } else {
    const int b2v = u - 8192;                 // 0..511
    const float* Wsrc = (b2v >= 256) ? W2 : W1;
    u16* wb = (b2v >= 256) ? w2b : w1b;
    const int off = (b2v & 255) * 1024;
    float4 v = ((const float4*)(Wsrc + off))[tid];
    ushort4 o; o.x = f2b(v.x); o.y = f2b(v.y); o.z = f2b(v.z); o.w = f2b(v.w);
    *(ushort4*)(wb + off + tid*4) = o;
  }
}

// ---------- P2: topk+setsums (blocks 0..7) || classsums-xr (blocks 8..263) ----------
__global__ __launch_bounds__(256) void k_tops(const float* __restrict__ fvp, const u16* __restrict__ xr,
                       int* __restrict__ meta, int* __restrict__ rowfl, float* __restrict__ xs) {
  const int tid = threadIdx.x;
  if (blockIdx.x < BB) {
    const int b = blockIdx.x;
    __shared__ float v[NN];
    __shared__ unsigned long long wk[8];
    __shared__ unsigned long long winner[2];
    __shared__ int sel[18];
    __shared__ int scnt[12];
    __shared__ int ccnt[12];
    const int wv = tid >> 6, ln = tid & 63;

    float lv[8];
    {
      f32x4 a0 = {0,0,0,0}, a1 = {0,0,0,0};
      for (int sb_ = 0; sb_ < 16; ++sb_) {
        const f32x4* p = (const f32x4*)(fvp + ((size_t)(b*16 + sb_))*NN + tid*8);
        a0 += p[0]; a1 += p[1];
      }
      lv[0]=a0[0]; lv[1]=a0[1]; lv[2]=a0[2]; lv[3]=a0[3];
      lv[4]=a1[0]; lv[5]=a1[1]; lv[6]=a1[2]; lv[7]=a1[3];
    }
    #pragma unroll
    for (int j = 0; j < 8; ++j) v[tid*8+j] = lv[j];

    unsigned long long kD[8], kA[8];
    #pragma unroll
    for (int j = 0; j < 8; ++j) {
      unsigned u = __float_as_uint(lv[j]);
      u = (u & 0x80000000u) ? ~u : (u | 0x80000000u);
      unsigned idx = (unsigned)(tid*8 + j);
      kD[j] = ((unsigned long long)u << 32) | (0xFFFFFFFFu - idx);
      kA[j] = ((unsigned long long)(~u) << 32) | (0xFFFFFFFFu - idx);
    }
    unsigned mskD = 0, mskA = 0;
    for (int r = 0; r < 9; ++r) {
      unsigned long long bD = 0ull, bA = 0ull;
      #pragma unroll
      for (int j = 0; j < 8; ++j) {
        if (!((mskD >> j) & 1) && kD[j] > bD) bD = kD[j];
        if (!((mskA >> j) & 1) && kA[j] > bA) bA = kA[j];
      }
      #pragma unroll
      for (int o = 32; o > 0; o >>= 1) {
        unsigned long long oD = __shfl_xor(bD, o, 64);
        unsigned long long oA = __shfl_xor(bA, o, 64);
        if (oD > bD) bD = oD;
        if (oA > bA) bA = oA;
      }
      if (ln == 0) { wk[wv] = bD; wk[4+wv] = bA; }
      __syncthreads();
      if (tid == 0) {
        unsigned long long mD = wk[0], mA = wk[4];
        #pragma unroll
        for (int q = 1; q < 4; ++q) {
          if (wk[q] > mD) mD = wk[q];
          if (wk[4+q] > mA) mA = wk[4+q];
        }
        winner[0] = mD; winner[1] = mA;
        sel[r]   = (int)(0xFFFFFFFFu - (unsigned)mD);
        sel[9+r] = (int)(0xFFFFFFFFu - (unsigned)mA);
      }
      __syncthreads();
      unsigned iD = 0xFFFFFFFFu - (unsigned)winner[0];
      unsigned iA = 0xFFFFFFFFu - (unsigned)winner[1];
      if ((int)(iD >> 3) == tid) mskD |= 1u << (iD & 7);
      if ((int)(iA >> 3) == tid) mskA |= 1u << (iA & 7);
    }

    int cp = 0, cn = 0, cz = 0;
    #pragma unroll
    for (int j = 0; j < 8; ++j) { cp += (lv[j] > 0.f); cn += (lv[j] < 0.f); cz += (lv[j] == 0.f); }
    #pragma unroll
    for (int o = 32; o > 0; o >>= 1) { cp += __shfl_xor(cp, o, 64); cn += __shfl_xor(cn, o, 64); cz += __shfl_xor(cz, o, 64); }
    if (ln == 0) { ccnt[wv] = cp; ccnt[4+wv] = cn; ccnt[8+wv] = cz; }
    __syncthreads();
    if (tid == 0) {
      int CP = 0, CN = 0, CZ = 0;
      #pragma unroll
      for (int q = 0; q < 4; ++q) { CP += ccnt[q]; CN += ccnt[4+q]; CZ += ccnt[8+q]; }
      scnt[0] = CP; scnt[1] = CN; scnt[2] = CZ;
      for (int t2 = 3; t2 < 12; ++t2) scnt[t2] = 0;
      for (int r = 1; r < 9; ++r) {
        float wD = v[sel[r]];   scnt[3] += (wD > 0.f); scnt[4] += (wD < 0.f); scnt[5] += (wD == 0.f);
        float wA = v[sel[9+r]]; scnt[6] += (wA > 0.f); scnt[7] += (wA < 0.f); scnt[8] += (wA == 0.f);
        float wZ = v[r];        scnt[9] += (wZ > 0.f); scnt[10] += (wZ < 0.f); scnt[11] += (wZ == 0.f);
      }
    }
    __syncthreads();
    #pragma unroll
    for (int j = 0; j < 8; ++j) {
      const int i = tid*8 + j;
      float w = lv[j];
      int cls = (w > 0.f) ? 0 : ((w < 0.f) ? 1 : 2);
      int mD = 0, mA = 0;
      #pragma unroll
      for (int r = 1; r < 9; ++r) { mD |= (sel[r] == i); mA |= (sel[9+r] == i); }
      int mZ8 = (i >= 1 && i <= 8);
      rowfl[b*NN + i] = cls | (mD << 2) | (mA << 3) | (mZ8 << 4);
    }
    if (tid < 18) meta[b*32 + tid] = sel[tid];
    if (tid >= 18 && tid < 30) meta[b*32 + tid] = scnt[tid - 18];
    __syncthreads();
    // set sums of xr over D/A/Z8 rows (single-writer, rows 3..11 of xs)
    #pragma unroll
    for (int half = 0; half < 2; ++half) {
      const int d = tid + half*256;
      float a[9];
      #pragma unroll
      for (int q = 0; q < 9; ++q) a[q] = 0.f;
      for (int r = 1; r < 9; ++r) {
        int iD = sel[r];   float wD = v[iD]; int cD = (wD>0.f)?0:((wD<0.f)?1:2);
        a[cD]   += b2f(xr[((size_t)b*NN + iD)*512 + d]);
        int iA = sel[9+r]; float wA = v[iA]; int cA = (wA>0.f)?0:((wA<0.f)?1:2);
        a[3+cA] += b2f(xr[((size_t)b*NN + iA)*512 + d]);
        float wZ = v[r];   int cZ = (wZ>0.f)?0:((wZ<0.f)?1:2);
        a[6+cZ] += b2f(xr[((size_t)b*NN + r)*512 + d]);
      }
      #pragma unroll
      for (int q = 0; q < 9; ++q) xs[((size_t)b*12 + 3 + q)*512 + d] = a[q];
    }
  } else {
    const int u = blockIdx.x - 8, b = u >> 5, c = u & 31, n0 = c*64;
    __shared__ f32x8 red[12][64];
    __shared__ int scls[64];
    if (tid < 64) {
      float s = 0.f;
      for (int sb_ = 0; sb_ < 16; ++sb_) s += fvp[((size_t)(b*16 + sb_))*NN + n0 + tid];
      scls[tid] = (s > 0.f) ? 0 : ((s < 0.f) ? 1 : 2);
    }
    __syncthreads();
    const int fc = tid & 63, rg = tid >> 6;
    f32x8 sp = {0,0,0,0,0,0,0,0}, sn = sp, sz = sp;
    for (int it = 0; it < 16; ++it) {
      const int nr = rg + it*4;
      const int cls = scls[nr];
      f32x8 hf = b2f8(*(const u16x8*)(xr + ((size_t)b*NN + n0 + nr)*512 + fc*8));
      if (cls == 0) sp += hf; else if (cls == 1) sn += hf; else sz += hf;
    }
    red[0*4+rg][fc] = sp; red[1*4+rg][fc] = sn; red[2*4+rg][fc] = sz;
    __syncthreads();
    if (rg == 0) {
      sp = red[0][fc] + red[1][fc] + red[2][fc] + red[3][fc];
      sn = red[4][fc] + red[5][fc] + red[6][fc] + red[7][fc];
      sz = red[8][fc] + red[9][fc] + red[10][fc] + red[11][fc];
      #pragma unroll
      for (int j = 0; j < 8; ++j) {
        atomicAdd(&xs[((size_t)b*12 + 0)*512 + fc*8 + j], sp[j]);
        atomicAdd(&xs[((size_t)b*12 + 1)*512 + fc*8 + j], sn[j]);
        atomicAdd(&xs[((size_t)b*12 + 2)*512 + fc*8 + j], sz[j]);
      }
    }
  }
}

// ---------- P4: g1 sums (setsums blocks 0..7 || classsums 8..263) ----------
__global__ __launch_bounds__(256) void k_sums(const u16* __restrict__ g1, const int* __restrict__ meta,
                      const int* __restrict__ rowfl, float* __restrict__ g1s) {
  const int tid = threadIdx.x;
  if (blockIdx.x < BB) {
    const int b = blockIdx.x;
    const int* mb = meta + b*32;
    #pragma unroll
    for (int half = 0; half < 2; ++half) {
      const int d = tid + half*256;
      float a[9];
      #pragma unroll
      for (int q = 0; q < 9; ++q) a[q] = 0.f;
      for (int r = 1; r < 9; ++r) {
        int iD = mb[r];   int cD = rowfl[b*NN + iD] & 3;
        a[cD]   += b2f(g1[((size_t)b*NN + iD)*512 + d]);
        int iA = mb[9+r]; int cA = rowfl[b*NN + iA] & 3;
        a[3+cA] += b2f(g1[((size_t)b*NN + iA)*512 + d]);
        int cZ = rowfl[b*NN + r] & 3;
        a[6+cZ] += b2f(g1[((size_t)b*NN + r)*512 + d]);
      }
      #pragma unroll
      for (int q = 0; q < 9; ++q) g1s[((size_t)b*12 + 3 + q)*512 + d] = a[q];
    }
  } else {
    const int u = blockIdx.x - 8, b = u >> 5, c = u & 31, n0 = c*64;
    __shared__ f32x8 red[12][64];
    __shared__ int scls[64];
    if (tid < 64) scls[tid] = rowfl[b*NN + n0 + tid] & 3;
    __syncthreads();
    const int fc = tid & 63, rg = tid >> 6;
    f32x8 sp = {0,0,0,0,0,0,0,0}, sn = sp, sz = sp;
    for (int it = 0; it < 16; ++it) {
      const int nr = rg + it*4;
      const int cls = scls[nr];
      f32x8 hf = b2f8(*(const u16x8*)(g1 + ((size_t)b*NN + n0 + nr)*512 + fc*8));
      if (cls == 0) sp += hf; else if (cls == 1) sn += hf; else sz += hf;
    }
    red[0*4+rg][fc] = sp; red[1*4+rg][fc] = sn; red[2*4+rg][fc] = sz;
    __syncthreads();
    if (rg == 0) {
      sp = red[0][fc] + red[1][fc] + red[2][fc] + red[3][fc];
      sn = red[4][fc] + red[5][fc] + red[6][fc] + red[7][fc];
      sz = red[8][fc] + red[9][fc] + red[10][fc] + red[11][fc];
      #pragma unroll
      for (int j = 0; j < 8; ++j) {
        atomicAdd(&g1s[((size_t)b*12 + 0)*512 + fc*8 + j], sp[j]);
        atomicAdd(&g1s[((size_t)b*12 + 1)*512 + fc*8 + j], sn[j]);
        atomicAdd(&g1s[((size_t)b*12 + 2)*512 + fc*8 + j], sz[j]);
      }
    }
  }
}

// ---------- GEMM fused with V-table MFMA: MODE 0 = layer1 (relu->bf16 g1), MODE 1 = layer2 (+transpose->out) ----------
template<int MODE>
__global__ __launch_bounds__(256, 2) void k_gemmf(const u16* __restrict__ A, const u16* __restrict__ Bw,
                       const float* __restrict__ bias, const float* __restrict__ sums,
                       const int* __restrict__ meta, const int* __restrict__ rowfl,
                       void* __restrict__ outp) {
  __shared__ __align__(16) char SM[33152];
  u16* As  = (u16*)SM;             // 8192 B
  u16* Bs  = (u16*)(SM + 8192);    // 8192 B
  u16* xsb = (u16*)(SM + 16384);   // 16*520*2 = 16640 B
  int* cnt = (int*)(SM + 33088);   // 48 B
  const int tid = threadIdx.x;
  const int w = tid >> 6, l = tid & 63;
  const int wm = w >> 1, wn = w & 1;
  int m0, n0; remap_mn(blockIdx.x, m0, n0);
  const int b = m0 >> 11;

  // prologue: sums f32 [12][512] -> xsb bf16 [16][520]; cnt
  for (int i = tid; i < 12*512; i += 256) {
    const int s = i >> 9, k = i & 511;
    xsb[s*520 + k] = f2b(sums[(size_t)b*12*512 + i]);
  }
  for (int i = tid; i < 4*520; i += 256) xsb[12*520 + i] = 0;
  if (tid < 12) cnt[tid] = meta[b*32 + 18 + tid];

  f32x4 acc[4][4]; f32x4 accV[4];
  #pragma unroll
  for (int i = 0; i < 4; ++i) {
    accV[i] = (f32x4){0.f, 0.f, 0.f, 0.f};
    #pragma unroll
    for (int j = 0; j < 4; ++j) acc[i][j] = (f32x4){0.f, 0.f, 0.f, 0.f};
  }
  const int srow = l >> 2, skk = (l & 3) * 8;
  const int lr = l & 15, lk = (l >> 4) * 8;
  for (int kt = 0; kt < 512; kt += 32) {
    #pragma unroll
    for (int p = 0; p < 2; ++p) {
      const int q = w*2 + p;
      GLOAD16(A  + (size_t)(m0 + q*16 + srow)*512 + kt + skk, As + q*512);
      GLOAD16(Bw + (size_t)(n0 + q*16 + srow)*512 + kt + skk, Bs + q*512);
    }
    __syncthreads();
    bf16x8 af[4], bfr[4];
    #pragma unroll
    for (int i = 0; i < 4; ++i) af[i] = *(const bf16x8*)(As + (wm*64 + i*16 + lr)*32 + lk);
    #pragma unroll
    for (int j = 0; j < 4; ++j) bfr[j] = *(const bf16x8*)(Bs + (wn*64 + j*16 + lr)*32 + lk);
    #pragma unroll
    for (int i = 0; i < 4; ++i)
      #pragma unroll
      for (int j = 0; j < 4; ++j)
        acc[i][j] = __builtin_amdgcn_mfma_f32_16x16x32_bf16(bfr[j], af[i], acc[i][j], 0, 0, 0);
    if (wm == 0) {   // V-slice MFMA: D[s][n] for 12 sum-rows
      bf16x8 afx = *(const bf16x8*)(xsb + lr*520 + kt + lk);
      #pragma unroll
      for (int j = 0; j < 4; ++j)
        accV[j] = __builtin_amdgcn_mfma_f32_16x16x32_bf16(afx, bfr[j], accV[j], 0, 0, 0);
    }
    __syncthreads();
  }

  // Vl[12][128] f32 at SM+0 (As region dead)
  float* Vl = (float*)SM;
  if (wm == 0) {
    #pragma unroll
    for (int j = 0; j < 4; ++j) {
      const int c = wn*64 + j*16 + lr;
      const float bv = bias[n0 + c];
      #pragma unroll
      for (int r = 0; r < 4; ++r) {
        const int s = (l >> 4)*4 + r;
        if (s < 12) Vl[s*128 + c] = accV[j][r] + (float)cnt[s] * bv;
      }
    }
  }
  __syncthreads();

  int fl[4]; float rdg[4]; bool cs[4];
  #pragma unroll
  for (int i = 0; i < 4; ++i) {
    const int m = m0 + wm*64 + i*16 + lr;
    const int f = rowfl[m];
    fl[i] = f;
    const int cls = f & 3;
    const int bD = (f >> 2) & 1, bA = (f >> 3) & 1, bZ = (f >> 4) & 1;
    const int rb = 3 + cls*3;
    const int c3c = bD*cnt[0] + bA*cnt[1] + bZ*cnt[2];
    const int c2c = cnt[rb] + cnt[rb+1] + cnt[rb+2] - bD*cnt[rb] - bA*cnt[rb+1] - bZ*cnt[rb+2];
    cs[i] = (cls == 0 && bD) || (cls == 1 && bA) || (cls == 2 && bZ);
    float deg = (float)(c3c + c2c) + (cs[i] ? 0.f : 1.f);
    if (deg < 1.f) deg = 1.f;
    rdg[i] = 1.f / deg;
  }

  if (MODE == 0) {
    u16* G = (u16*)outp;
    #pragma unroll
    for (int j = 0; j < 4; ++j) {
      const int dgb = n0 + wn*64 + j*16 + (l >> 4)*4;
      u16x4 o[4];
      #pragma unroll
      for (int r = 0; r < 4; ++r) {
        const int c = wn*64 + j*16 + (l >> 4)*4 + r;
        const float bv = bias[dgb + r];
        float vl[12];
        #pragma unroll
        for (int s = 0; s < 12; ++s) vl[s] = Vl[s*128 + c];
        #pragma unroll
        for (int i = 0; i < 4; ++i) {
          const int f = fl[i], cls = f & 3, rb = 3 + cls*3;
          float c3 = ((f&4)?vl[0]:0.f) + ((f&8)?vl[1]:0.f) + ((f&16)?vl[2]:0.f);
          float c2 = vl[rb] + vl[rb+1] + vl[rb+2]
                   - ((f&4)?vl[rb]:0.f) - ((f&8)?vl[rb+1]:0.f) - ((f&16)?vl[rb+2]:0.f);
          float val = (c3 + c2) * rdg[i];
          if (!cs[i]) val += (acc[i][j][r] + bv) * rdg[i];
          o[i][r] = f2b(fmaxf(val, 0.f));
        }
      }
      #pragma unroll
      for (int i = 0; i < 4; ++i)
        *(u16x4*)(G + (size_t)(m0 + wm*64 + i*16 + lr)*512 + dgb) = o[i];
    }
  } else {
    float* out = (float*)outp;
    float (*ep)[130] = (float(*)[130])(SM + 8192);   // 32 rows x 130 f32 = 16640 B, after Vl
    const int nloc = m0 & 2047;
    for (int j = 0; j < 4; ++j) {
      #pragma unroll
      for (int r = 0; r < 4; ++r) {
        const int c = wn*64 + j*16 + (l >> 4)*4 + r;
        const float bv = bias[n0 + c];
        float vl[12];
        #pragma unroll
        for (int s = 0; s < 12; ++s) vl[s] = Vl[s*128 + c];
        #pragma unroll
        for (int i = 0; i < 4; ++i) {
          const int f = fl[i], cls = f & 3, rb = 3 + cls*3;
          float c3 = ((f&4)?vl[0]:0.f) + ((f&8)?vl[1]:0.f) + ((f&16)?vl[2]:0.f);
          float c2 = vl[rb] + vl[rb+1] + vl[rb+2]
                   - ((f&4)?vl[rb]:0.f) - ((f&8)?vl[rb+1]:0.f) - ((f&16)?vl[rb+2]:0.f);
          float val = (c3 + c2) * rdg[i];
          if (!cs[i]) val += (acc[i][j][r] + bv) * rdg[i];
          ep[wn*16 + (l >> 4)*4 + r][wm*64 + i*16 + lr] = val;
        }
      }
      __syncthreads();
      // drain all 32 ep rows: 4 waves x 8 rows x (64 lanes x f32x2 = 128 m)
      #pragma unroll
      for (int rr = 0; rr < 8; ++rr) {
        const int q = w*8 + rr;
        const int s = n0 + (q >> 4)*64 + j*16 + (q & 15);
        float2 v2 = *(const float2*)&ep[q][2*l];
        *(float2*)(out + ((size_t)b*SS + s)*NN + nloc + 2*l) = v2;
      }
      __syncthreads();
    }
  }
}

extern "C" void kernel_launch(void* const* d_in, const int* in_sizes, int n_in,
                              void* d_out, int out_size, void* d_ws, size_t ws_size,
                              hipStream_t stream) {
  const float* x  = (const float*)d_in[0];
  const float* W1 = (const float*)d_in[1];
  const float* b1 = (const float*)d_in[2];
  const float* W2 = (const float*)d_in[3];
  const float* b2 = (const float*)d_in[4];
  float* out = (float*)d_out;
  char* ws = (char*)d_ws;

  float* fvp   = (float*)(ws + 0);           // 1 MB
  int*   meta  = (int*)  (ws + 1048576);     // 1 KB
  int*   rowfl = (int*)  (ws + 1049600);     // 64 KB
  float* xs    = (float*)(ws + 1115136);     // 192 KB  [b][12][512] f32
  float* g1s   = (float*)(ws + 1311744);     // 192 KB  (contiguous after xs for zeroing)
  u16*   w1b   = (u16*)  (ws + 1508352);     // 512 KB
  u16*   w2b   = (u16*)  (ws + 2032640);     // 512 KB
  u16*   g1    = (u16*)  (ws + 2556928);     // 16 MB
  u16*   xr    = (u16*)  (ws + 19334144);    // 16 MB

  k_prep<<<8704, dim3(32, 8), 0, stream>>>(x, xr, fvp, W1, W2, w1b, w2b, xs);
  k_tops<<<264, 256, 0, stream>>>(fvp, xr, meta, rowfl, xs);
  k_gemmf<0><<<512, 256, 0, stream>>>(xr, w1b, b1, xs, meta, rowfl, (void*)g1);
  k_sums<<<264, 256, 0, stream>>>(g1, meta, rowfl, g1s);
  k_gemmf<1><<<512, 256, 0, stream>>>(g1, w2b, b2, g1s, meta, rowfl, (void*)out);
}

// Round 10
// 116.060 us; speedup vs baseline: 8.4288x; 1.4310x over previous
//
#include <hip/hip_runtime.h>
#include <hip/hip_bf16.h>
#include <cstdint>

typedef unsigned short u16;
typedef __bf16 bf16x8 __attribute__((ext_vector_type(8)));
typedef float f32x4 __attribute__((ext_vector_type(4)));
typedef float f32x8 __attribute__((ext_vector_type(8)));
typedef unsigned short u16x4 __attribute__((ext_vector_type(4)));
typedef unsigned short u16x8 __attribute__((ext_vector_type(8)));

#define BB 8
#define SS 512
#define NN 2048
#define HH 512
#define MM (BB*NN)   // 16384

__device__ inline u16 f2b(float f) {
  __hip_bfloat16 h = __float2bfloat16(f);
  return *reinterpret_cast<u16*>(&h);
}
__device__ inline float b2f(u16 u) {
  unsigned x = ((unsigned)u) << 16;
  return __uint_as_float(x);
}
__device__ inline f32x8 b2f8(u16x8 v) {
  f32x8 r;
  #pragma unroll
  for (int k = 0; k < 8; ++k) r[k] = b2f(v[k]);
  return r;
}

#define GLOAD16(g, l) __builtin_amdgcn_global_load_lds( \
    (const __attribute__((address_space(1))) void*)(g), \
    (__attribute__((address_space(3))) void*)(l), 16, 0, 0)

// XCD-aware remap: 4 n-tiles of one m-tile run consecutively on one XCD (A-panel L2 reuse)
__device__ inline void remap_mn(int bid, int& m0, int& n0) {
  const int xcd = bid & 7, k = bid >> 3;   // 512 % 8 == 0 -> bijective
  m0 = (xcd * 16 + (k >> 2)) * 128;
  n0 = (k & 3) * 128;
}

// ---------- P1: transpose x -> xr bf16 + fvp partials; weight bf16 cast; zero xs/g1s bins ----------
__global__ __launch_bounds__(256) void k_prep(const float* __restrict__ x, u16* __restrict__ xr,
                       float* __restrict__ fvp,
                       const float* __restrict__ W1, const float* __restrict__ W2,
                       u16* __restrict__ w1b, u16* __restrict__ w2b,
                       float* __restrict__ xs /* xs+g1s contiguous */) {
  __shared__ float t[32][33];
  __shared__ float ps[8][32];
  const int u = blockIdx.x;
  const int tx = threadIdx.x, ty = threadIdx.y;
  const int tid = ty*32 + tx;
  if (u < 8192) {
    const int n0 = (u & 63) * 32, st = (u >> 6) & 15, b = u >> 10;
    const int s0 = st * 32;
    float acc = 0.f;
    for (int i = ty; i < 32; i += 8) {
      float w = x[(size_t)b*SS*NN + (size_t)(s0+i)*NN + (n0+tx)];
      t[i][tx] = w; acc += w;
    }
    ps[ty][tx] = acc;
    __syncthreads();
    if (ty == 0) {
      float s = 0.f;
      #pragma unroll
      for (int j = 0; j < 8; ++j) s += ps[j][tx];
      fvp[((size_t)(b*16 + st))*NN + n0 + tx] = s;
    }
    for (int i = ty; i < 32; i += 8)
      xr[((size_t)b*NN + (n0+i))*SS + (s0+tx)] = f2b(t[tx][i]);
    if (u < 96) {   // zero xs + g1s (2 * 8*12*512 f32 = 24576 float4)
      ((float4*)xs)[u*256 + tid] = make_float4(0.f, 0.f, 0.f, 0.f);
    }
  } else {
    const int b2v = u - 8192;                 // 0..511
    const float* Wsrc = (b2v >= 256) ? W2 : W1;
    u16* wb = (b2v >= 256) ? w2b : w1b;
    const int off = (b2v & 255) * 1024;
    float4 v = ((const float4*)(Wsrc + off))[tid];
    ushort4 o; o.x = f2b(v.x); o.y = f2b(v.y); o.z = f2b(v.z); o.w = f2b(v.w);
    *(ushort4*)(wb + off + tid*4) = o;
  }
}

// ---------- P2: topk+setsums (blocks 0..7) || classsums-xr (blocks 8..263) ----------
__global__ __launch_bounds__(256) void k_tops(const float* __restrict__ fvp, const u16* __restrict__ xr,
                       int* __restrict__ meta, int* __restrict__ rowfl, float* __restrict__ xs) {
  const int tid = threadIdx.x;
  if (blockIdx.x < BB) {
    const int b = blockIdx.x;
    __shared__ float v[NN];
    __shared__ unsigned long long wk[8];
    __shared__ unsigned long long winner[2];
    __shared__ int sel[18];
    __shared__ int scnt[12];
    __shared__ int ccnt[12];
    const int wv = tid >> 6, ln = tid & 63;

    float lv[8];
    {
      f32x4 a0 = {0,0,0,0}, a1 = {0,0,0,0};
      for (int sb_ = 0; sb_ < 16; ++sb_) {
        const f32x4* p = (const f32x4*)(fvp + ((size_t)(b*16 + sb_))*NN + tid*8);
        a0 += p[0]; a1 += p[1];
      }
      lv[0]=a0[0]; lv[1]=a0[1]; lv[2]=a0[2]; lv[3]=a0[3];
      lv[4]=a1[0]; lv[5]=a1[1]; lv[6]=a1[2]; lv[7]=a1[3];
    }
    #pragma unroll
    for (int j = 0; j < 8; ++j) v[tid*8+j] = lv[j];

    unsigned long long kD[8], kA[8];
    #pragma unroll
    for (int j = 0; j < 8; ++j) {
      unsigned u = __float_as_uint(lv[j]);
      u = (u & 0x80000000u) ? ~u : (u | 0x80000000u);
      unsigned idx = (unsigned)(tid*8 + j);
      kD[j] = ((unsigned long long)u << 32) | (0xFFFFFFFFu - idx);
      kA[j] = ((unsigned long long)(~u) << 32) | (0xFFFFFFFFu - idx);
    }
    unsigned mskD = 0, mskA = 0;
    for (int r = 0; r < 9; ++r) {
      unsigned long long bD = 0ull, bA = 0ull;
      #pragma unroll
      for (int j = 0; j < 8; ++j) {
        if (!((mskD >> j) & 1) && kD[j] > bD) bD = kD[j];
        if (!((mskA >> j) & 1) && kA[j] > bA) bA = kA[j];
      }
      #pragma unroll
      for (int o = 32; o > 0; o >>= 1) {
        unsigned long long oD = __shfl_xor(bD, o, 64);
        unsigned long long oA = __shfl_xor(bA, o, 64);
        if (oD > bD) bD = oD;
        if (oA > bA) bA = oA;
      }
      if (ln == 0) { wk[wv] = bD; wk[4+wv] = bA; }
      __syncthreads();
      if (tid == 0) {
        unsigned long long mD = wk[0], mA = wk[4];
        #pragma unroll
        for (int q = 1; q < 4; ++q) {
          if (wk[q] > mD) mD = wk[q];
          if (wk[4+q] > mA) mA = wk[4+q];
        }
        winner[0] = mD; winner[1] = mA;
        sel[r]   = (int)(0xFFFFFFFFu - (unsigned)mD);
        sel[9+r] = (int)(0xFFFFFFFFu - (unsigned)mA);
      }
      __syncthreads();
      unsigned iD = 0xFFFFFFFFu - (unsigned)winner[0];
      unsigned iA = 0xFFFFFFFFu - (unsigned)winner[1];
      if ((int)(iD >> 3) == tid) mskD |= 1u << (iD & 7);
      if ((int)(iA >> 3) == tid) mskA |= 1u << (iA & 7);
    }

    int cp = 0, cn = 0, cz = 0;
    #pragma unroll
    for (int j = 0; j < 8; ++j) { cp += (lv[j] > 0.f); cn += (lv[j] < 0.f); cz += (lv[j] == 0.f); }
    #pragma unroll
    for (int o = 32; o > 0; o >>= 1) { cp += __shfl_xor(cp, o, 64); cn += __shfl_xor(cn, o, 64); cz += __shfl_xor(cz, o, 64); }
    if (ln == 0) { ccnt[wv] = cp; ccnt[4+wv] = cn; ccnt[8+wv] = cz; }
    __syncthreads();
    if (tid == 0) {
      int CP = 0, CN = 0, CZ = 0;
      #pragma unroll
      for (int q = 0; q < 4; ++q) { CP += ccnt[q]; CN += ccnt[4+q]; CZ += ccnt[8+q]; }
      scnt[0] = CP; scnt[1] = CN; scnt[2] = CZ;
      for (int t2 = 3; t2 < 12; ++t2) scnt[t2] = 0;
      for (int r = 1; r < 9; ++r) {
        float wD = v[sel[r]];   scnt[3] += (wD > 0.f); scnt[4] += (wD < 0.f); scnt[5] += (wD == 0.f);
        float wA = v[sel[9+r]]; scnt[6] += (wA > 0.f); scnt[7] += (wA < 0.f); scnt[8] += (wA == 0.f);
        float wZ = v[r];        scnt[9] += (wZ > 0.f); scnt[10] += (wZ < 0.f); scnt[11] += (wZ == 0.f);
      }
    }
    __syncthreads();
    #pragma unroll
    for (int j = 0; j < 8; ++j) {
      const int i = tid*8 + j;
      float w = lv[j];
      int cls = (w > 0.f) ? 0 : ((w < 0.f) ? 1 : 2);
      int mD = 0, mA = 0;
      #pragma unroll
      for (int r = 1; r < 9; ++r) { mD |= (sel[r] == i); mA |= (sel[9+r] == i); }
      int mZ8 = (i >= 1 && i <= 8);
      rowfl[b*NN + i] = cls | (mD << 2) | (mA << 3) | (mZ8 << 4);
    }
    if (tid < 18) meta[b*32 + tid] = sel[tid];
    if (tid >= 18 && tid < 30) meta[b*32 + tid] = scnt[tid - 18];
    __syncthreads();
    // set sums of xr over D/A/Z8 rows (single-writer, rows 3..11 of xs) — static-indexed accumulators
    #pragma unroll
    for (int half = 0; half < 2; ++half) {
      const int d = tid + half*256;
      float a[9];
      #pragma unroll
      for (int q = 0; q < 9; ++q) a[q] = 0.f;
      for (int r = 1; r < 9; ++r) {
        int iD = sel[r];   float wD = v[iD]; int cD = (wD>0.f)?0:((wD<0.f)?1:2);
        float vD = b2f(xr[((size_t)b*NN + iD)*512 + d]);
        int iA = sel[9+r]; float wA = v[iA]; int cA = (wA>0.f)?0:((wA<0.f)?1:2);
        float vA = b2f(xr[((size_t)b*NN + iA)*512 + d]);
        float wZ = v[r];   int cZ = (wZ>0.f)?0:((wZ<0.f)?1:2);
        float vZ = b2f(xr[((size_t)b*NN + r)*512 + d]);
        #pragma unroll
        for (int q = 0; q < 3; ++q) {
          a[q]   += (cD == q) ? vD : 0.f;
          a[3+q] += (cA == q) ? vA : 0.f;
          a[6+q] += (cZ == q) ? vZ : 0.f;
        }
      }
      #pragma unroll
      for (int q = 0; q < 9; ++q) xs[((size_t)b*12 + 3 + q)*512 + d] = a[q];
    }
  } else {
    const int u = blockIdx.x - 8, b = u >> 5, c = u & 31, n0 = c*64;
    __shared__ f32x8 red[12][64];
    __shared__ int scls[64];
    if (tid < 64) {
      float s = 0.f;
      for (int sb_ = 0; sb_ < 16; ++sb_) s += fvp[((size_t)(b*16 + sb_))*NN + n0 + tid];
      scls[tid] = (s > 0.f) ? 0 : ((s < 0.f) ? 1 : 2);
    }
    __syncthreads();
    const int fc = tid & 63, rg = tid >> 6;
    f32x8 sp = {0,0,0,0,0,0,0,0}, sn = sp, sz = sp;
    for (int it = 0; it < 16; ++it) {
      const int nr = rg + it*4;
      const int cls = scls[nr];
      f32x8 hf = b2f8(*(const u16x8*)(xr + ((size_t)b*NN + n0 + nr)*512 + fc*8));
      if (cls == 0) sp += hf; else if (cls == 1) sn += hf; else sz += hf;
    }
    red[0*4+rg][fc] = sp; red[1*4+rg][fc] = sn; red[2*4+rg][fc] = sz;
    __syncthreads();
    if (rg == 0) {
      sp = red[0][fc] + red[1][fc] + red[2][fc] + red[3][fc];
      sn = red[4][fc] + red[5][fc] + red[6][fc] + red[7][fc];
      sz = red[8][fc] + red[9][fc] + red[10][fc] + red[11][fc];
      #pragma unroll
      for (int j = 0; j < 8; ++j) {
        atomicAdd(&xs[((size_t)b*12 + 0)*512 + fc*8 + j], sp[j]);
        atomicAdd(&xs[((size_t)b*12 + 1)*512 + fc*8 + j], sn[j]);
        atomicAdd(&xs[((size_t)b*12 + 2)*512 + fc*8 + j], sz[j]);
      }
    }
  }
}

// ---------- P4: g1 sums (setsums blocks 0..7 || classsums 8..263) ----------
__global__ __launch_bounds__(256) void k_sums(const u16* __restrict__ g1, const int* __restrict__ meta,
                      const int* __restrict__ rowfl, float* __restrict__ g1s) {
  const int tid = threadIdx.x;
  if (blockIdx.x < BB) {
    const int b = blockIdx.x;
    const int* mb = meta + b*32;
    #pragma unroll
    for (int half = 0; half < 2; ++half) {
      const int d = tid + half*256;
      float a[9];
      #pragma unroll
      for (int q = 0; q < 9; ++q) a[q] = 0.f;
      for (int r = 1; r < 9; ++r) {
        int iD = mb[r];   int cD = rowfl[b*NN + iD] & 3;
        float vD = b2f(g1[((size_t)b*NN + iD)*512 + d]);
        int iA = mb[9+r]; int cA = rowfl[b*NN + iA] & 3;
        float vA = b2f(g1[((size_t)b*NN + iA)*512 + d]);
        int cZ = rowfl[b*NN + r] & 3;
        float vZ = b2f(g1[((size_t)b*NN + r)*512 + d]);
        #pragma unroll
        for (int q = 0; q < 3; ++q) {
          a[q]   += (cD == q) ? vD : 0.f;
          a[3+q] += (cA == q) ? vA : 0.f;
          a[6+q] += (cZ == q) ? vZ : 0.f;
        }
      }
      #pragma unroll
      for (int q = 0; q < 9; ++q) g1s[((size_t)b*12 + 3 + q)*512 + d] = a[q];
    }
  } else {
    const int u = blockIdx.x - 8, b = u >> 5, c = u & 31, n0 = c*64;
    __shared__ f32x8 red[12][64];
    __shared__ int scls[64];
    if (tid < 64) scls[tid] = rowfl[b*NN + n0 + tid] & 3;
    __syncthreads();
    const int fc = tid & 63, rg = tid >> 6;
    f32x8 sp = {0,0,0,0,0,0,0,0}, sn = sp, sz = sp;
    for (int it = 0; it < 16; ++it) {
      const int nr = rg + it*4;
      const int cls = scls[nr];
      f32x8 hf = b2f8(*(const u16x8*)(g1 + ((size_t)b*NN + n0 + nr)*512 + fc*8));
      if (cls == 0) sp += hf; else if (cls == 1) sn += hf; else sz += hf;
    }
    red[0*4+rg][fc] = sp; red[1*4+rg][fc] = sn; red[2*4+rg][fc] = sz;
    __syncthreads();
    if (rg == 0) {
      sp = red[0][fc] + red[1][fc] + red[2][fc] + red[3][fc];
      sn = red[4][fc] + red[5][fc] + red[6][fc] + red[7][fc];
      sz = red[8][fc] + red[9][fc] + red[10][fc] + red[11][fc];
      #pragma unroll
      for (int j = 0; j < 8; ++j) {
        atomicAdd(&g1s[((size_t)b*12 + 0)*512 + fc*8 + j], sp[j]);
        atomicAdd(&g1s[((size_t)b*12 + 1)*512 + fc*8 + j], sn[j]);
        atomicAdd(&g1s[((size_t)b*12 + 2)*512 + fc*8 + j], sz[j]);
      }
    }
  }
}

// ---------- GEMM fused with V-table MFMA: MODE 0 = layer1 (relu->bf16 g1), MODE 1 = layer2 (+transpose->out) ----------
template<int MODE>
__global__ __launch_bounds__(256, 2) void k_gemmf(const u16* __restrict__ A, const u16* __restrict__ Bw,
                       const float* __restrict__ bias, const float* __restrict__ sums,
                       const int* __restrict__ meta, const int* __restrict__ rowfl,
                       void* __restrict__ outp) {
  __shared__ __align__(16) char SM[33152];
  u16* As  = (u16*)SM;             // 8192 B
  u16* Bs  = (u16*)(SM + 8192);    // 8192 B
  u16* xsb = (u16*)(SM + 16384);   // 16*520*2 = 16640 B
  int* cnt = (int*)(SM + 33088);   // 48 B
  const int tid = threadIdx.x;
  const int w = tid >> 6, l = tid & 63;
  const int wm = w >> 1, wn = w & 1;
  int m0, n0; remap_mn(blockIdx.x, m0, n0);
  const int b = m0 >> 11;

  // prologue: sums f32 [12][512] -> xsb bf16 [16][520]; cnt
  for (int i = tid; i < 12*512; i += 256) {
    const int s = i >> 9, k = i & 511;
    xsb[s*520 + k] = f2b(sums[(size_t)b*12*512 + i]);
  }
  for (int i = tid; i < 4*520; i += 256) xsb[12*520 + i] = 0;
  if (tid < 12) cnt[tid] = meta[b*32 + 18 + tid];

  f32x4 acc[4][4]; f32x4 accV[4];
  #pragma unroll
  for (int i = 0; i < 4; ++i) {
    accV[i] = (f32x4){0.f, 0.f, 0.f, 0.f};
    #pragma unroll
    for (int j = 0; j < 4; ++j) acc[i][j] = (f32x4){0.f, 0.f, 0.f, 0.f};
  }
  const int srow = l >> 2, skk = (l & 3) * 8;
  const int lr = l & 15, lk = (l >> 4) * 8;
  for (int kt = 0; kt < 512; kt += 32) {
    #pragma unroll
    for (int p = 0; p < 2; ++p) {
      const int q = w*2 + p;
      GLOAD16(A  + (size_t)(m0 + q*16 + srow)*512 + kt + skk, As + q*512);
      GLOAD16(Bw + (size_t)(n0 + q*16 + srow)*512 + kt + skk, Bs + q*512);
    }
    __syncthreads();
    bf16x8 af[4], bfr[4];
    #pragma unroll
    for (int i = 0; i < 4; ++i) af[i] = *(const bf16x8*)(As + (wm*64 + i*16 + lr)*32 + lk);
    #pragma unroll
    for (int j = 0; j < 4; ++j) bfr[j] = *(const bf16x8*)(Bs + (wn*64 + j*16 + lr)*32 + lk);
    #pragma unroll
    for (int i = 0; i < 4; ++i)
      #pragma unroll
      for (int j = 0; j < 4; ++j)
        acc[i][j] = __builtin_amdgcn_mfma_f32_16x16x32_bf16(bfr[j], af[i], acc[i][j], 0, 0, 0);
    if (wm == 0) {   // V-slice MFMA: D[s][n] for 12 sum-rows
      bf16x8 afx = *(const bf16x8*)(xsb + lr*520 + kt + lk);
      #pragma unroll
      for (int j = 0; j < 4; ++j)
        accV[j] = __builtin_amdgcn_mfma_f32_16x16x32_bf16(afx, bfr[j], accV[j], 0, 0, 0);
    }
    __syncthreads();
  }

  // Vl[12][128] f32 at SM+0 (As region dead)
  float* Vl = (float*)SM;
  if (wm == 0) {
    #pragma unroll
    for (int j = 0; j < 4; ++j) {
      const int c = wn*64 + j*16 + lr;
      const float bv = bias[n0 + c];
      #pragma unroll
      for (int r = 0; r < 4; ++r) {
        const int s = (l >> 4)*4 + r;
        if (s < 12) Vl[s*128 + c] = accV[j][r] + (float)cnt[s] * bv;
      }
    }
  }
  __syncthreads();

  int fl[4]; float rdg[4]; bool cs[4];
  const float* Vb[4];   // per-i class-row base into Vl (LDS pointer, static offsets below)
  #pragma unroll
  for (int i = 0; i < 4; ++i) {
    const int m = m0 + wm*64 + i*16 + lr;
    const int f = rowfl[m];
    fl[i] = f;
    const int cls = f & 3;
    const int bD = (f >> 2) & 1, bA = (f >> 3) & 1, bZ = (f >> 4) & 1;
    const int rb = 3 + cls*3;
    const int c3c = bD*cnt[0] + bA*cnt[1] + bZ*cnt[2];
    const int c2c = cnt[rb] + cnt[rb+1] + cnt[rb+2] - bD*cnt[rb] - bA*cnt[rb+1] - bZ*cnt[rb+2];
    cs[i] = (cls == 0 && bD) || (cls == 1 && bA) || (cls == 2 && bZ);
    float deg = (float)(c3c + c2c) + (cs[i] ? 0.f : 1.f);
    if (deg < 1.f) deg = 1.f;
    rdg[i] = 1.f / deg;
    Vb[i] = Vl + rb*128;
  }

  if (MODE == 0) {
    u16* G = (u16*)outp;
    #pragma unroll
    for (int j = 0; j < 4; ++j) {
      const int dgb = n0 + wn*64 + j*16 + (l >> 4)*4;
      u16x4 o[4];
      #pragma unroll
      for (int r = 0; r < 4; ++r) {
        const int c = wn*64 + j*16 + (l >> 4)*4 + r;
        const float bv = bias[dgb + r];
        const float v0 = Vl[c], v1 = Vl[128 + c], v2 = Vl[256 + c];
        #pragma unroll
        for (int i = 0; i < 4; ++i) {
          const int f = fl[i];
          const float t0 = Vb[i][c], t1 = Vb[i][128 + c], t2 = Vb[i][256 + c];
          float c3 = ((f&4)?v0:0.f) + ((f&8)?v1:0.f) + ((f&16)?v2:0.f);
          float c2 = t0 + t1 + t2
                   - ((f&4)?t0:0.f) - ((f&8)?t1:0.f) - ((f&16)?t2:0.f);
          float val = (c3 + c2) * rdg[i];
          if (!cs[i]) val += (acc[i][j][r] + bv) * rdg[i];
          o[i][r] = f2b(fmaxf(val, 0.f));
        }
      }
      #pragma unroll
      for (int i = 0; i < 4; ++i)
        *(u16x4*)(G + (size_t)(m0 + wm*64 + i*16 + lr)*512 + dgb) = o[i];
    }
  } else {
    float* out = (float*)outp;
    float (*ep)[130] = (float(*)[130])(SM + 8192);   // 32 rows x 130 f32 = 16640 B, after Vl
    const int nloc = m0 & 2047;
    for (int j = 0; j < 4; ++j) {
      #pragma unroll
      for (int r = 0; r < 4; ++r) {
        const int c = wn*64 + j*16 + (l >> 4)*4 + r;
        const float bv = bias[n0 + c];
        const float v0 = Vl[c], v1 = Vl[128 + c], v2 = Vl[256 + c];
        #pragma unroll
        for (int i = 0; i < 4; ++i) {
          const int f = fl[i];
          const float t0 = Vb[i][c], t1 = Vb[i][128 + c], t2 = Vb[i][256 + c];
          float c3 = ((f&4)?v0:0.f) + ((f&8)?v1:0.f) + ((f&16)?v2:0.f);
          float c2 = t0 + t1 + t2
                   - ((f&4)?t0:0.f) - ((f&8)?t1:0.f) - ((f&16)?t2:0.f);
          float val = (c3 + c2) * rdg[i];
          if (!cs[i]) val += (acc[i][j][r] + bv) * rdg[i];
          ep[wn*16 + (l >> 4)*4 + r][wm*64 + i*16 + lr] = val;
        }
      }
      __syncthreads();
      // drain all 32 ep rows: 4 waves x 8 rows x (64 lanes x f32x2 = 128 m)
      #pragma unroll
      for (int rr = 0; rr < 8; ++rr) {
        const int q = w*8 + rr;
        const int s = n0 + (q >> 4)*64 + j*16 + (q & 15);
        float2 v2 = *(const float2*)&ep[q][2*l];
        *(float2*)(out + ((size_t)b*SS + s)*NN + nloc + 2*l) = v2;
      }
      __syncthreads();
    }
  }
}

extern "C" void kernel_launch(void* const* d_in, const int* in_sizes, int n_in,
                              void* d_out, int out_size, void* d_ws, size_t ws_size,
                              hipStream_t stream) {
  const float* x  = (const float*)d_in[0];
  const float* W1 = (const float*)d_in[1];
  const float* b1 = (const float*)d_in[2];
  const float* W2 = (const float*)d_in[3];
  const float* b2 = (const float*)d_in[4];
  float* out = (float*)d_out;
  char* ws = (char*)d_ws;

  float* fvp   = (float*)(ws + 0);           // 1 MB
  int*   meta  = (int*)  (ws + 1048576);     // 1 KB
  int*   rowfl = (int*)  (ws + 1049600);     // 64 KB
  float* xs    = (float*)(ws + 1115136);     // 192 KB  [b][12][512] f32
  float* g1s   = (float*)(ws + 1311744);     // 192 KB  (contiguous after xs for zeroing)
  u16*   w1b   = (u16*)  (ws + 1508352);     // 512 KB
  u16*   w2b   = (u16*)  (ws + 2032640);     // 512 KB
  u16*   g1    = (u16*)  (ws + 2556928);     // 16 MB
  u16*   xr    = (u16*)  (ws + 19334144);    // 16 MB

  k_prep<<<8704, dim3(32, 8), 0, stream>>>(x, xr, fvp, W1, W2, w1b, w2b, xs);
  k_tops<<<264, 256, 0, stream>>>(fvp, xr, meta, rowfl, xs);
  k_gemmf<0><<<512, 256, 0, stream>>>(xr, w1b, b1, xs, meta, rowfl, (void*)g1);
  k_sums<<<264, 256, 0, stream>>>(g1, meta, rowfl, g1s);
  k_gemmf<1><<<512, 256, 0, stream>>>(g1, w2b, b2, g1s, meta, rowfl, (void*)out);
}

// Round 11
// 112.896 us; speedup vs baseline: 8.6651x; 1.0280x over previous
//
#include <hip/hip_runtime.h>
#include <hip/hip_bf16.h>
#include <cstdint>

typedef unsigned short u16;
typedef __bf16 bf16x8 __attribute__((ext_vector_type(8)));
typedef float f32x4 __attribute__((ext_vector_type(4)));
typedef float f32x8 __attribute__((ext_vector_type(8)));
typedef unsigned short u16x4 __attribute__((ext_vector_type(4)));
typedef unsigned short u16x8 __attribute__((ext_vector_type(8)));

#define BB 8
#define SS 512
#define NN 2048
#define HH 512
#define MM (BB*NN)   // 16384

__device__ inline u16 f2b(float f) {
  __hip_bfloat16 h = __float2bfloat16(f);
  return *reinterpret_cast<u16*>(&h);
}
__device__ inline float b2f(u16 u) {
  unsigned x = ((unsigned)u) << 16;
  return __uint_as_float(x);
}
__device__ inline f32x8 b2f8(u16x8 v) {
  f32x8 r;
  #pragma unroll
  for (int k = 0; k < 8; ++k) r[k] = b2f(v[k]);
  return r;
}

#define GLOAD16(g, l) __builtin_amdgcn_global_load_lds( \
    (const __attribute__((address_space(1))) void*)(g), \
    (__attribute__((address_space(3))) void*)(l), 16, 0, 0)

// XCD-aware remap: 4 n-tiles of one m-tile run consecutively on one XCD (A-panel L2 reuse)
__device__ inline void remap_mn(int bid, int& m0, int& n0) {
  const int xcd = bid & 7, k = bid >> 3;   // 512 % 8 == 0 -> bijective
  m0 = (xcd * 16 + (k >> 2)) * 128;
  n0 = (k & 3) * 128;
}

// ---------- P1: transpose x -> xr bf16 (ushort4 writes) + fvp partials (8 per batch); weight cast; zero xs/g1s ----------
__global__ __launch_bounds__(256) void k_prep(const float* __restrict__ x, u16* __restrict__ xr,
                       float* __restrict__ fvp,
                       const float* __restrict__ W1, const float* __restrict__ W2,
                       u16* __restrict__ w1b, u16* __restrict__ w2b,
                       float* __restrict__ xs /* xs+g1s contiguous */) {
  const int u = blockIdx.x;
  const int tid = threadIdx.x;
  if (u < 4096) {
    __shared__ float t[64][33];     // [s_local][n_local]
    __shared__ float ps[8][32];
    const int tx = tid & 31, ty = tid >> 5;
    const int n0 = (u & 63) * 32, st = (u >> 6) & 7, b = u >> 9;
    const int s0 = st * 64;
    float acc = 0.f;
    #pragma unroll
    for (int i = ty; i < 64; i += 8) {
      float w = x[(size_t)b*SS*NN + (size_t)(s0+i)*NN + n0 + tx];
      t[i][tx] = w; acc += w;
    }
    ps[ty][tx] = acc;
    __syncthreads();
    if (ty == 0) {
      float s = 0.f;
      #pragma unroll
      for (int j = 0; j < 8; ++j) s += ps[j][tx];
      fvp[((size_t)(b*8 + st))*NN + n0 + tx] = s;
    }
    const int wtx = tid & 15, wty = tid >> 4;
    #pragma unroll
    for (int j = wty; j < 32; j += 16) {
      ushort4 o;
      o.x = f2b(t[wtx*4+0][j]); o.y = f2b(t[wtx*4+1][j]);
      o.z = f2b(t[wtx*4+2][j]); o.w = f2b(t[wtx*4+3][j]);
      *(ushort4*)(xr + ((size_t)b*NN + n0 + j)*SS + s0 + wtx*4) = o;
    }
    if (u < 96) {   // zero xs + g1s (2 * 8*12*512 f32 = 24576 float4)
      ((float4*)xs)[u*256 + tid] = make_float4(0.f, 0.f, 0.f, 0.f);
    }
  } else {
    const int b2v = u - 4096;                 // 0..511
    const float* Wsrc = (b2v >= 256) ? W2 : W1;
    u16* wb = (b2v >= 256) ? w2b : w1b;
    const int off = (b2v & 255) * 1024;
    float4 v = ((const float4*)(Wsrc + off))[tid];
    ushort4 o; o.x = f2b(v.x); o.y = f2b(v.y); o.z = f2b(v.z); o.w = f2b(v.w);
    *(ushort4*)(wb + off + tid*4) = o;
  }
}

// ---------- P2: topk+setsums (blocks 0..7) || classsums-xr (blocks 8..263) ----------
__global__ __launch_bounds__(256) void k_tops(const float* __restrict__ fvp, const u16* __restrict__ xr,
                       int* __restrict__ meta, int* __restrict__ rowfl, float* __restrict__ xs) {
  const int tid = threadIdx.x;
  if (blockIdx.x < BB) {
    const int b = blockIdx.x;
    __shared__ float v[NN];
    __shared__ unsigned long long wk[8];
    __shared__ unsigned long long winner[2];
    __shared__ int sel[18];
    __shared__ int scnt[12];
    __shared__ int ccnt[12];
    const int wv = tid >> 6, ln = tid & 63;

    float lv[8];
    {
      f32x4 a0 = {0,0,0,0}, a1 = {0,0,0,0};
      for (int sb_ = 0; sb_ < 8; ++sb_) {
        const f32x4* p = (const f32x4*)(fvp + ((size_t)(b*8 + sb_))*NN + tid*8);
        a0 += p[0]; a1 += p[1];
      }
      lv[0]=a0[0]; lv[1]=a0[1]; lv[2]=a0[2]; lv[3]=a0[3];
      lv[4]=a1[0]; lv[5]=a1[1]; lv[6]=a1[2]; lv[7]=a1[3];
    }
    #pragma unroll
    for (int j = 0; j < 8; ++j) v[tid*8+j] = lv[j];

    unsigned long long kD[8], kA[8];
    #pragma unroll
    for (int j = 0; j < 8; ++j) {
      unsigned u = __float_as_uint(lv[j]);
      u = (u & 0x80000000u) ? ~u : (u | 0x80000000u);
      unsigned idx = (unsigned)(tid*8 + j);
      kD[j] = ((unsigned long long)u << 32) | (0xFFFFFFFFu - idx);
      kA[j] = ((unsigned long long)(~u) << 32) | (0xFFFFFFFFu - idx);
    }
    unsigned mskD = 0, mskA = 0;
    for (int r = 0; r < 9; ++r) {
      unsigned long long bD = 0ull, bA = 0ull;
      #pragma unroll
      for (int j = 0; j < 8; ++j) {
        if (!((mskD >> j) & 1) && kD[j] > bD) bD = kD[j];
        if (!((mskA >> j) & 1) && kA[j] > bA) bA = kA[j];
      }
      #pragma unroll
      for (int o = 32; o > 0; o >>= 1) {
        unsigned long long oD = __shfl_xor(bD, o, 64);
        unsigned long long oA = __shfl_xor(bA, o, 64);
        if (oD > bD) bD = oD;
        if (oA > bA) bA = oA;
      }
      if (ln == 0) { wk[wv] = bD; wk[4+wv] = bA; }
      __syncthreads();
      if (tid == 0) {
        unsigned long long mD = wk[0], mA = wk[4];
        #pragma unroll
        for (int q = 1; q < 4; ++q) {
          if (wk[q] > mD) mD = wk[q];
          if (wk[4+q] > mA) mA = wk[4+q];
        }
        winner[0] = mD; winner[1] = mA;
        sel[r]   = (int)(0xFFFFFFFFu - (unsigned)mD);
        sel[9+r] = (int)(0xFFFFFFFFu - (unsigned)mA);
      }
      __syncthreads();
      unsigned iD = 0xFFFFFFFFu - (unsigned)winner[0];
      unsigned iA = 0xFFFFFFFFu - (unsigned)winner[1];
      if ((int)(iD >> 3) == tid) mskD |= 1u << (iD & 7);
      if ((int)(iA >> 3) == tid) mskA |= 1u << (iA & 7);
    }

    int cp = 0, cn = 0, cz = 0;
    #pragma unroll
    for (int j = 0; j < 8; ++j) { cp += (lv[j] > 0.f); cn += (lv[j] < 0.f); cz += (lv[j] == 0.f); }
    #pragma unroll
    for (int o = 32; o > 0; o >>= 1) { cp += __shfl_xor(cp, o, 64); cn += __shfl_xor(cn, o, 64); cz += __shfl_xor(cz, o, 64); }
    if (ln == 0) { ccnt[wv] = cp; ccnt[4+wv] = cn; ccnt[8+wv] = cz; }
    __syncthreads();
    if (tid == 0) {
      int CP = 0, CN = 0, CZ = 0;
      #pragma unroll
      for (int q = 0; q < 4; ++q) { CP += ccnt[q]; CN += ccnt[4+q]; CZ += ccnt[8+q]; }
      scnt[0] = CP; scnt[1] = CN; scnt[2] = CZ;
      for (int t2 = 3; t2 < 12; ++t2) scnt[t2] = 0;
      for (int r = 1; r < 9; ++r) {
        float wD = v[sel[r]];   scnt[3] += (wD > 0.f); scnt[4] += (wD < 0.f); scnt[5] += (wD == 0.f);
        float wA = v[sel[9+r]]; scnt[6] += (wA > 0.f); scnt[7] += (wA < 0.f); scnt[8] += (wA == 0.f);
        float wZ = v[r];        scnt[9] += (wZ > 0.f); scnt[10] += (wZ < 0.f); scnt[11] += (wZ == 0.f);
      }
    }
    __syncthreads();
    #pragma unroll
    for (int j = 0; j < 8; ++j) {
      const int i = tid*8 + j;
      float w = lv[j];
      int cls = (w > 0.f) ? 0 : ((w < 0.f) ? 1 : 2);
      int mD = 0, mA = 0;
      #pragma unroll
      for (int r = 1; r < 9; ++r) { mD |= (sel[r] == i); mA |= (sel[9+r] == i); }
      int mZ8 = (i >= 1 && i <= 8);
      rowfl[b*NN + i] = cls | (mD << 2) | (mA << 3) | (mZ8 << 4);
    }
    if (tid < 18) meta[b*32 + tid] = sel[tid];
    if (tid >= 18 && tid < 30) meta[b*32 + tid] = scnt[tid - 18];
    __syncthreads();
    // set sums of xr over D/A/Z8 rows (single-writer, rows 3..11 of xs) — static-indexed accumulators
    #pragma unroll
    for (int half = 0; half < 2; ++half) {
      const int d = tid + half*256;
      float a[9];
      #pragma unroll
      for (int q = 0; q < 9; ++q) a[q] = 0.f;
      for (int r = 1; r < 9; ++r) {
        int iD = sel[r];   float wD = v[iD]; int cD = (wD>0.f)?0:((wD<0.f)?1:2);
        float vD = b2f(xr[((size_t)b*NN + iD)*512 + d]);
        int iA = sel[9+r]; float wA = v[iA]; int cA = (wA>0.f)?0:((wA<0.f)?1:2);
        float vA = b2f(xr[((size_t)b*NN + iA)*512 + d]);
        float wZ = v[r];   int cZ = (wZ>0.f)?0:((wZ<0.f)?1:2);
        float vZ = b2f(xr[((size_t)b*NN + r)*512 + d]);
        #pragma unroll
        for (int q = 0; q < 3; ++q) {
          a[q]   += (cD == q) ? vD : 0.f;
          a[3+q] += (cA == q) ? vA : 0.f;
          a[6+q] += (cZ == q) ? vZ : 0.f;
        }
      }
      #pragma unroll
      for (int q = 0; q < 9; ++q) xs[((size_t)b*12 + 3 + q)*512 + d] = a[q];
    }
  } else {
    const int u = blockIdx.x - 8, b = u >> 5, c = u & 31, n0 = c*64;
    __shared__ f32x8 red[12][64];
    __shared__ int scls[64];
    if (tid < 64) {
      float s = 0.f;
      for (int sb_ = 0; sb_ < 8; ++sb_) s += fvp[((size_t)(b*8 + sb_))*NN + n0 + tid];
      scls[tid] = (s > 0.f) ? 0 : ((s < 0.f) ? 1 : 2);
    }
    __syncthreads();
    const int fc = tid & 63, rg = tid >> 6;
    f32x8 sp = {0,0,0,0,0,0,0,0}, sn = sp, sz = sp;
    for (int it = 0; it < 16; ++it) {
      const int nr = rg + it*4;
      const int cls = scls[nr];
      f32x8 hf = b2f8(*(const u16x8*)(xr + ((size_t)b*NN + n0 + nr)*512 + fc*8));
      if (cls == 0) sp += hf; else if (cls == 1) sn += hf; else sz += hf;
    }
    red[0*4+rg][fc] = sp; red[1*4+rg][fc] = sn; red[2*4+rg][fc] = sz;
    __syncthreads();
    if (rg == 0) {
      sp = red[0][fc] + red[1][fc] + red[2][fc] + red[3][fc];
      sn = red[4][fc] + red[5][fc] + red[6][fc] + red[7][fc];
      sz = red[8][fc] + red[9][fc] + red[10][fc] + red[11][fc];
      #pragma unroll
      for (int j = 0; j < 8; ++j) {
        atomicAdd(&xs[((size_t)b*12 + 0)*512 + fc*8 + j], sp[j]);
        atomicAdd(&xs[((size_t)b*12 + 1)*512 + fc*8 + j], sn[j]);
        atomicAdd(&xs[((size_t)b*12 + 2)*512 + fc*8 + j], sz[j]);
      }
    }
  }
}

// ---------- P4: g1 sums (setsums blocks 0..7 || classsums 8..263) ----------
__global__ __launch_bounds__(256) void k_sums(const u16* __restrict__ g1, const int* __restrict__ meta,
                      const int* __restrict__ rowfl, float* __restrict__ g1s) {
  const int tid = threadIdx.x;
  if (blockIdx.x < BB) {
    const int b = blockIdx.x;
    const int* mb = meta + b*32;
    #pragma unroll
    for (int half = 0; half < 2; ++half) {
      const int d = tid + half*256;
      float a[9];
      #pragma unroll
      for (int q = 0; q < 9; ++q) a[q] = 0.f;
      for (int r = 1; r < 9; ++r) {
        int iD = mb[r];   int cD = rowfl[b*NN + iD] & 3;
        float vD = b2f(g1[((size_t)b*NN + iD)*512 + d]);
        int iA = mb[9+r]; int cA = rowfl[b*NN + iA] & 3;
        float vA = b2f(g1[((size_t)b*NN + iA)*512 + d]);
        int cZ = rowfl[b*NN + r] & 3;
        float vZ = b2f(g1[((size_t)b*NN + r)*512 + d]);
        #pragma unroll
        for (int q = 0; q < 3; ++q) {
          a[q]   += (cD == q) ? vD : 0.f;
          a[3+q] += (cA == q) ? vA : 0.f;
          a[6+q] += (cZ == q) ? vZ : 0.f;
        }
      }
      #pragma unroll
      for (int q = 0; q < 9; ++q) g1s[((size_t)b*12 + 3 + q)*512 + d] = a[q];
    }
  } else {
    const int u = blockIdx.x - 8, b = u >> 5, c = u & 31, n0 = c*64;
    __shared__ f32x8 red[12][64];
    __shared__ int scls[64];
    if (tid < 64) scls[tid] = rowfl[b*NN + n0 + tid] & 3;
    __syncthreads();
    const int fc = tid & 63, rg = tid >> 6;
    f32x8 sp = {0,0,0,0,0,0,0,0}, sn = sp, sz = sp;
    for (int it = 0; it < 16; ++it) {
      const int nr = rg + it*4;
      const int cls = scls[nr];
      f32x8 hf = b2f8(*(const u16x8*)(g1 + ((size_t)b*NN + n0 + nr)*512 + fc*8));
      if (cls == 0) sp += hf; else if (cls == 1) sn += hf; else sz += hf;
    }
    red[0*4+rg][fc] = sp; red[1*4+rg][fc] = sn; red[2*4+rg][fc] = sz;
    __syncthreads();
    if (rg == 0) {
      sp = red[0][fc] + red[1][fc] + red[2][fc] + red[3][fc];
      sn = red[4][fc] + red[5][fc] + red[6][fc] + red[7][fc];
      sz = red[8][fc] + red[9][fc] + red[10][fc] + red[11][fc];
      #pragma unroll
      for (int j = 0; j < 8; ++j) {
        atomicAdd(&g1s[((size_t)b*12 + 0)*512 + fc*8 + j], sp[j]);
        atomicAdd(&g1s[((size_t)b*12 + 1)*512 + fc*8 + j], sn[j]);
        atomicAdd(&g1s[((size_t)b*12 + 2)*512 + fc*8 + j], sz[j]);
      }
    }
  }
}

// ---------- GEMM fused with V-table MFMA: MODE 0 = layer1 (relu->bf16 g1), MODE 1 = layer2 (+transpose->out) ----------
// LDS XOR swizzle (slot ^= (row>>1)&3) on A/B: pre-swizzled global source (linear gload_lds dest)
// + matching XOR on fragment reads -> 8-way bank conflict becomes 2-way (free).
template<int MODE>
__global__ __launch_bounds__(256, 2) void k_gemmf(const u16* __restrict__ A, const u16* __restrict__ Bw,
                       const float* __restrict__ bias, const float* __restrict__ sums,
                       const int* __restrict__ meta, const int* __restrict__ rowfl,
                       void* __restrict__ outp) {
  __shared__ __align__(16) char SM[33152];
  u16* As  = (u16*)SM;             // 8192 B
  u16* Bs  = (u16*)(SM + 8192);    // 8192 B
  u16* xsb = (u16*)(SM + 16384);   // 16*520*2 = 16640 B
  int* cnt = (int*)(SM + 33088);   // 48 B
  const int tid = threadIdx.x;
  const int w = tid >> 6, l = tid & 63;
  const int wm = w >> 1, wn = w & 1;
  int m0, n0; remap_mn(blockIdx.x, m0, n0);
  const int b = m0 >> 11;

  // prologue: sums f32 [12][512] -> xsb bf16 [16][520]; cnt
  for (int i = tid; i < 12*512; i += 256) {
    const int s = i >> 9, k = i & 511;
    xsb[s*520 + k] = f2b(sums[(size_t)b*12*512 + i]);
  }
  for (int i = tid; i < 4*520; i += 256) xsb[12*520 + i] = 0;
  if (tid < 12) cnt[tid] = meta[b*32 + 18 + tid];

  f32x4 acc[4][4]; f32x4 accV[4];
  #pragma unroll
  for (int i = 0; i < 4; ++i) {
    accV[i] = (f32x4){0.f, 0.f, 0.f, 0.f};
    #pragma unroll
    for (int j = 0; j < 4; ++j) acc[i][j] = (f32x4){0.f, 0.f, 0.f, 0.f};
  }
  const int srow = l >> 2;
  const int sslot = (l & 3) ^ ((l >> 3) & 3);    // pre-swizzled source 16B-slot
  const int skk = sslot * 8;
  const int lr = l & 15;
  const int g = l >> 4;                          // desired global k-slot of the fragment
  const int lkA = ((g ^ ((lr >> 1) & 3)) * 8);   // swizzled LDS read offset (elements)
  const int lk = g * 8;                          // xsb (unswizzled) read offset
  for (int kt = 0; kt < 512; kt += 32) {
    #pragma unroll
    for (int p = 0; p < 2; ++p) {
      const int q = w*2 + p;
      GLOAD16(A  + (size_t)(m0 + q*16 + srow)*512 + kt + skk, As + q*512);
      GLOAD16(Bw + (size_t)(n0 + q*16 + srow)*512 + kt + skk, Bs + q*512);
    }
    __syncthreads();
    bf16x8 af[4], bfr[4];
    #pragma unroll
    for (int i = 0; i < 4; ++i) af[i] = *(const bf16x8*)(As + (wm*64 + i*16 + lr)*32 + lkA);
    #pragma unroll
    for (int j = 0; j < 4; ++j) bfr[j] = *(const bf16x8*)(Bs + (wn*64 + j*16 + lr)*32 + lkA);
    #pragma unroll
    for (int i = 0; i < 4; ++i)
      #pragma unroll
      for (int j = 0; j < 4; ++j)
        acc[i][j] = __builtin_amdgcn_mfma_f32_16x16x32_bf16(bfr[j], af[i], acc[i][j], 0, 0, 0);
    if (wm == 0) {   // V-slice MFMA: D[s][n] for 12 sum-rows
      bf16x8 afx = *(const bf16x8*)(xsb + lr*520 + kt + lk);
      #pragma unroll
      for (int j = 0; j < 4; ++j)
        accV[j] = __builtin_amdgcn_mfma_f32_16x16x32_bf16(afx, bfr[j], accV[j], 0, 0, 0);
    }
    __syncthreads();
  }

  // Vl[12][128] f32 at SM+0 (As region dead)
  float* Vl = (float*)SM;
  if (wm == 0) {
    #pragma unroll
    for (int j = 0; j < 4; ++j) {
      const int c = wn*64 + j*16 + lr;
      const float bv = bias[n0 + c];
      #pragma unroll
      for (int r = 0; r < 4; ++r) {
        const int s = (l >> 4)*4 + r;
        if (s < 12) Vl[s*128 + c] = accV[j][r] + (float)cnt[s] * bv;
      }
    }
  }
  __syncthreads();

  int fl[4]; float rdg[4]; bool cs[4];
  const float* Vb[4];   // per-i class-row base into Vl (LDS pointer, static offsets below)
  #pragma unroll
  for (int i = 0; i < 4; ++i) {
    const int m = m0 + wm*64 + i*16 + lr;
    const int f = rowfl[m];
    fl[i] = f;
    const int cls = f & 3;
    const int bD = (f >> 2) & 1, bA = (f >> 3) & 1, bZ = (f >> 4) & 1;
    const int rb = 3 + cls*3;
    const int c3c = bD*cnt[0] + bA*cnt[1] + bZ*cnt[2];
    const int c2c = cnt[rb] + cnt[rb+1] + cnt[rb+2] - bD*cnt[rb] - bA*cnt[rb+1] - bZ*cnt[rb+2];
    cs[i] = (cls == 0 && bD) || (cls == 1 && bA) || (cls == 2 && bZ);
    float deg = (float)(c3c + c2c) + (cs[i] ? 0.f : 1.f);
    if (deg < 1.f) deg = 1.f;
    rdg[i] = 1.f / deg;
    Vb[i] = Vl + rb*128;
  }

  if (MODE == 0) {
    u16* G = (u16*)outp;
    #pragma unroll
    for (int j = 0; j < 4; ++j) {
      const int dgb = n0 + wn*64 + j*16 + (l >> 4)*4;
      u16x4 o[4];
      #pragma unroll
      for (int r = 0; r < 4; ++r) {
        const int c = wn*64 + j*16 + (l >> 4)*4 + r;
        const float bv = bias[dgb + r];
        const float v0 = Vl[c], v1 = Vl[128 + c], v2 = Vl[256 + c];
        #pragma unroll
        for (int i = 0; i < 4; ++i) {
          const int f = fl[i];
          const float t0 = Vb[i][c], t1 = Vb[i][128 + c], t2 = Vb[i][256 + c];
          float c3 = ((f&4)?v0:0.f) + ((f&8)?v1:0.f) + ((f&16)?v2:0.f);
          float c2 = t0 + t1 + t2
                   - ((f&4)?t0:0.f) - ((f&8)?t1:0.f) - ((f&16)?t2:0.f);
          float val = (c3 + c2) * rdg[i];
          if (!cs[i]) val += (acc[i][j][r] + bv) * rdg[i];
          o[i][r] = f2b(fmaxf(val, 0.f));
        }
      }
      #pragma unroll
      for (int i = 0; i < 4; ++i)
        *(u16x4*)(G + (size_t)(m0 + wm*64 + i*16 + lr)*512 + dgb) = o[i];
    }
  } else {
    float* out = (float*)outp;
    float (*ep)[130] = (float(*)[130])(SM + 8192);   // 32 rows x 130 f32 = 16640 B, after Vl
    const int nloc = m0 & 2047;
    for (int j = 0; j < 4; ++j) {
      #pragma unroll
      for (int r = 0; r < 4; ++r) {
        const int c = wn*64 + j*16 + (l >> 4)*4 + r;
        const float bv = bias[n0 + c];
        const float v0 = Vl[c], v1 = Vl[128 + c], v2 = Vl[256 + c];
        #pragma unroll
        for (int i = 0; i < 4; ++i) {
          const int f = fl[i];
          const float t0 = Vb[i][c], t1 = Vb[i][128 + c], t2 = Vb[i][256 + c];
          float c3 = ((f&4)?v0:0.f) + ((f&8)?v1:0.f) + ((f&16)?v2:0.f);
          float c2 = t0 + t1 + t2
                   - ((f&4)?t0:0.f) - ((f&8)?t1:0.f) - ((f&16)?t2:0.f);
          float val = (c3 + c2) * rdg[i];
          if (!cs[i]) val += (acc[i][j][r] + bv) * rdg[i];
          ep[wn*16 + (l >> 4)*4 + r][wm*64 + i*16 + lr] = val;
        }
      }
      __syncthreads();
      // drain all 32 ep rows: 4 waves x 8 rows x (64 lanes x f32x2 = 128 m)
      #pragma unroll
      for (int rr = 0; rr < 8; ++rr) {
        const int q = w*8 + rr;
        const int s = n0 + (q >> 4)*64 + j*16 + (q & 15);
        float2 v2 = *(const float2*)&ep[q][2*l];
        *(float2*)(out + ((size_t)b*SS + s)*NN + nloc + 2*l) = v2;
      }
      __syncthreads();
    }
  }
}

extern "C" void kernel_launch(void* const* d_in, const int* in_sizes, int n_in,
                              void* d_out, int out_size, void* d_ws, size_t ws_size,
                              hipStream_t stream) {
  const float* x  = (const float*)d_in[0];
  const float* W1 = (const float*)d_in[1];
  const float* b1 = (const float*)d_in[2];
  const float* W2 = (const float*)d_in[3];
  const float* b2 = (const float*)d_in[4];
  float* out = (float*)d_out;
  char* ws = (char*)d_ws;

  float* fvp   = (float*)(ws + 0);           // 512 KB (8*8*2048 f32)
  int*   meta  = (int*)  (ws + 1048576);     // 1 KB
  int*   rowfl = (int*)  (ws + 1049600);     // 64 KB
  float* xs    = (float*)(ws + 1115136);     // 192 KB  [b][12][512] f32
  float* g1s   = (float*)(ws + 1311744);     // 192 KB  (contiguous after xs for zeroing)
  u16*   w1b   = (u16*)  (ws + 1508352);     // 512 KB
  u16*   w2b   = (u16*)  (ws + 2032640);     // 512 KB
  u16*   g1    = (u16*)  (ws + 2556928);     // 16 MB
  u16*   xr    = (u16*)  (ws + 19334144);    // 16 MB

  k_prep<<<4608, 256, 0, stream>>>(x, xr, fvp, W1, W2, w1b, w2b, xs);
  k_tops<<<264, 256, 0, stream>>>(fvp, xr, meta, rowfl, xs);
  k_gemmf<0><<<512, 256, 0, stream>>>(xr, w1b, b1, xs, meta, rowfl, (void*)g1);
  k_sums<<<264, 256, 0, stream>>>(g1, meta, rowfl, g1s);
  k_gemmf<1><<<512, 256, 0, stream>>>(g1, w2b, b2, g1s, meta, rowfl, (void*)out);
}

// Round 15
// 97.558 us; speedup vs baseline: 10.0273x; 1.1572x over previous
//
#include <hip/hip_runtime.h>
#include <hip/hip_bf16.h>
#include <cstdint>

typedef unsigned short u16;
typedef __bf16 bf16x8 __attribute__((ext_vector_type(8)));
typedef float f32x4 __attribute__((ext_vector_type(4)));
typedef float f32x8 __attribute__((ext_vector_type(8)));
typedef unsigned short u16x4 __attribute__((ext_vector_type(4)));
typedef unsigned short u16x8 __attribute__((ext_vector_type(8)));

#define BB 8
#define SS 512
#define NN 2048
#define HH 512
#define MM (BB*NN)   // 16384

__device__ inline u16 f2b(float f) {
  __hip_bfloat16 h = __float2bfloat16(f);
  return *reinterpret_cast<u16*>(&h);
}
__device__ inline float b2f(u16 u) {
  unsigned x = ((unsigned)u) << 16;
  return __uint_as_float(x);
}
__device__ inline f32x8 b2f8(u16x8 v) {
  f32x8 r;
  #pragma unroll
  for (int k = 0; k < 8; ++k) r[k] = b2f(v[k]);
  return r;
}

#define GLOAD16(g, l) __builtin_amdgcn_global_load_lds( \
    (const __attribute__((address_space(1))) void*)(g), \
    (__attribute__((address_space(3))) void*)(l), 16, 0, 0)

// XCD-aware remap: 4 n-tiles of one m-tile run consecutively on one XCD (A-panel L2 reuse)
__device__ inline void remap_mn(int bid, int& m0, int& n0) {
  const int xcd = bid & 7, k = bid >> 3;   // 512 % 8 == 0 -> bijective
  m0 = (xcd * 16 + (k >> 2)) * 128;
  n0 = (k & 3) * 128;
}

// ---------- P1: transpose x -> xr bf16 (ushort4 writes) + fvp partials (8 per batch); weight cast; zero xs/g1s ----------
__global__ __launch_bounds__(256) void k_prep(const float* __restrict__ x, u16* __restrict__ xr,
                       float* __restrict__ fvp,
                       const float* __restrict__ W1, const float* __restrict__ W2,
                       u16* __restrict__ w1b, u16* __restrict__ w2b,
                       float* __restrict__ xs /* xs+g1s contiguous */) {
  const int u = blockIdx.x;
  const int tid = threadIdx.x;
  if (u < 4096) {
    __shared__ float t[64][33];     // [s_local][n_local]
    __shared__ float ps[8][32];
    const int tx = tid & 31, ty = tid >> 5;
    const int n0 = (u & 63) * 32, st = (u >> 6) & 7, b = u >> 9;
    const int s0 = st * 64;
    float acc = 0.f;
    #pragma unroll
    for (int i = ty; i < 64; i += 8) {
      float w = x[(size_t)b*SS*NN + (size_t)(s0+i)*NN + n0 + tx];
      t[i][tx] = w; acc += w;
    }
    ps[ty][tx] = acc;
    __syncthreads();
    if (ty == 0) {
      float s = 0.f;
      #pragma unroll
      for (int j = 0; j < 8; ++j) s += ps[j][tx];
      fvp[((size_t)(b*8 + st))*NN + n0 + tx] = s;
    }
    const int wtx = tid & 15, wty = tid >> 4;
    #pragma unroll
    for (int j = wty; j < 32; j += 16) {
      ushort4 o;
      o.x = f2b(t[wtx*4+0][j]); o.y = f2b(t[wtx*4+1][j]);
      o.z = f2b(t[wtx*4+2][j]); o.w = f2b(t[wtx*4+3][j]);
      *(ushort4*)(xr + ((size_t)b*NN + n0 + j)*SS + s0 + wtx*4) = o;
    }
    if (u < 96) {   // zero xs + g1s (2 * 8*12*512 f32 = 24576 float4)
      ((float4*)xs)[u*256 + tid] = make_float4(0.f, 0.f, 0.f, 0.f);
    }
  } else {
    const int b2v = u - 4096;                 // 0..511
    const float* Wsrc = (b2v >= 256) ? W2 : W1;
    u16* wb = (b2v >= 256) ? w2b : w1b;
    const int off = (b2v & 255) * 1024;
    float4 v = ((const float4*)(Wsrc + off))[tid];
    ushort4 o; o.x = f2b(v.x); o.y = f2b(v.y); o.z = f2b(v.z); o.w = f2b(v.w);
    *(ushort4*)(wb + off + tid*4) = o;
  }
}

// ---------- P2: topk+setsums (blocks 0..7) || classsums-xr (blocks 8..263) ----------
__global__ __launch_bounds__(256) void k_tops(const float* __restrict__ fvp, const u16* __restrict__ xr,
                       int* __restrict__ meta, int* __restrict__ rowfl, float* __restrict__ xs) {
  const int tid = threadIdx.x;
  if (blockIdx.x < BB) {
    const int b = blockIdx.x;
    __shared__ float v[NN];
    __shared__ unsigned long long wk[8];
    __shared__ unsigned long long winner[2];
    __shared__ int sel[18];
    __shared__ int scnt[12];
    __shared__ int ccnt[12];
    const int wv = tid >> 6, ln = tid & 63;

    float lv[8];
    {
      f32x4 a0 = {0,0,0,0}, a1 = {0,0,0,0};
      for (int sb_ = 0; sb_ < 8; ++sb_) {
        const f32x4* p = (const f32x4*)(fvp + ((size_t)(b*8 + sb_))*NN + tid*8);
        a0 += p[0]; a1 += p[1];
      }
      lv[0]=a0[0]; lv[1]=a0[1]; lv[2]=a0[2]; lv[3]=a0[3];
      lv[4]=a1[0]; lv[5]=a1[1]; lv[6]=a1[2]; lv[7]=a1[3];
    }
    #pragma unroll
    for (int j = 0; j < 8; ++j) v[tid*8+j] = lv[j];

    unsigned long long kD[8], kA[8];
    #pragma unroll
    for (int j = 0; j < 8; ++j) {
      unsigned u = __float_as_uint(lv[j]);
      u = (u & 0x80000000u) ? ~u : (u | 0x80000000u);
      unsigned idx = (unsigned)(tid*8 + j);
      kD[j] = ((unsigned long long)u << 32) | (0xFFFFFFFFu - idx);
      kA[j] = ((unsigned long long)(~u) << 32) | (0xFFFFFFFFu - idx);
    }
    unsigned mskD = 0, mskA = 0;
    for (int r = 0; r < 9; ++r) {
      unsigned long long bD = 0ull, bA = 0ull;
      #pragma unroll
      for (int j = 0; j < 8; ++j) {
        if (!((mskD >> j) & 1) && kD[j] > bD) bD = kD[j];
        if (!((mskA >> j) & 1) && kA[j] > bA) bA = kA[j];
      }
      #pragma unroll
      for (int o = 32; o > 0; o >>= 1) {
        unsigned long long oD = __shfl_xor(bD, o, 64);
        unsigned long long oA = __shfl_xor(bA, o, 64);
        if (oD > bD) bD = oD;
        if (oA > bA) bA = oA;
      }
      if (ln == 0) { wk[wv] = bD; wk[4+wv] = bA; }
      __syncthreads();
      if (tid == 0) {
        unsigned long long mD = wk[0], mA = wk[4];
        #pragma unroll
        for (int q = 1; q < 4; ++q) {
          if (wk[q] > mD) mD = wk[q];
          if (wk[4+q] > mA) mA = wk[4+q];
        }
        winner[0] = mD; winner[1] = mA;
        sel[r]   = (int)(0xFFFFFFFFu - (unsigned)mD);
        sel[9+r] = (int)(0xFFFFFFFFu - (unsigned)mA);
      }
      __syncthreads();
      unsigned iD = 0xFFFFFFFFu - (unsigned)winner[0];
      unsigned iA = 0xFFFFFFFFu - (unsigned)winner[1];
      if ((int)(iD >> 3) == tid) mskD |= 1u << (iD & 7);
      if ((int)(iA >> 3) == tid) mskA |= 1u << (iA & 7);
    }

    int cp = 0, cn = 0, cz = 0;
    #pragma unroll
    for (int j = 0; j < 8; ++j) { cp += (lv[j] > 0.f); cn += (lv[j] < 0.f); cz += (lv[j] == 0.f); }
    #pragma unroll
    for (int o = 32; o > 0; o >>= 1) { cp += __shfl_xor(cp, o, 64); cn += __shfl_xor(cn, o, 64); cz += __shfl_xor(cz, o, 64); }
    if (ln == 0) { ccnt[wv] = cp; ccnt[4+wv] = cn; ccnt[8+wv] = cz; }
    __syncthreads();
    if (tid == 0) {
      int CP = 0, CN = 0, CZ = 0;
      #pragma unroll
      for (int q = 0; q < 4; ++q) { CP += ccnt[q]; CN += ccnt[4+q]; CZ += ccnt[8+q]; }
      scnt[0] = CP; scnt[1] = CN; scnt[2] = CZ;
      for (int t2 = 3; t2 < 12; ++t2) scnt[t2] = 0;
      for (int r = 1; r < 9; ++r) {
        float wD = v[sel[r]];   scnt[3] += (wD > 0.f); scnt[4] += (wD < 0.f); scnt[5] += (wD == 0.f);
        float wA = v[sel[9+r]]; scnt[6] += (wA > 0.f); scnt[7] += (wA < 0.f); scnt[8] += (wA == 0.f);
        float wZ = v[r];        scnt[9] += (wZ > 0.f); scnt[10] += (wZ < 0.f); scnt[11] += (wZ == 0.f);
      }
    }
    __syncthreads();
    #pragma unroll
    for (int j = 0; j < 8; ++j) {
      const int i = tid*8 + j;
      float w = lv[j];
      int cls = (w > 0.f) ? 0 : ((w < 0.f) ? 1 : 2);
      int mD = 0, mA = 0;
      #pragma unroll
      for (int r = 1; r < 9; ++r) { mD |= (sel[r] == i); mA |= (sel[9+r] == i); }
      int mZ8 = (i >= 1 && i <= 8);
      rowfl[b*NN + i] = cls | (mD << 2) | (mA << 3) | (mZ8 << 4);
    }
    if (tid < 18) meta[b*32 + tid] = sel[tid];
    if (tid >= 18 && tid < 30) meta[b*32 + tid] = scnt[tid - 18];
    __syncthreads();
    // set sums of xr over D/A/Z8 rows (single-writer, rows 3..11 of xs) — static-indexed accumulators
    #pragma unroll
    for (int half = 0; half < 2; ++half) {
      const int d = tid + half*256;
      float a[9];
      #pragma unroll
      for (int q = 0; q < 9; ++q) a[q] = 0.f;
      for (int r = 1; r < 9; ++r) {
        int iD = sel[r];   float wD = v[iD]; int cD = (wD>0.f)?0:((wD<0.f)?1:2);
        float vD = b2f(xr[((size_t)b*NN + iD)*512 + d]);
        int iA = sel[9+r]; float wA = v[iA]; int cA = (wA>0.f)?0:((wA<0.f)?1:2);
        float vA = b2f(xr[((size_t)b*NN + iA)*512 + d]);
        float wZ = v[r];   int cZ = (wZ>0.f)?0:((wZ<0.f)?1:2);
        float vZ = b2f(xr[((size_t)b*NN + r)*512 + d]);
        #pragma unroll
        for (int q = 0; q < 3; ++q) {
          a[q]   += (cD == q) ? vD : 0.f;
          a[3+q] += (cA == q) ? vA : 0.f;
          a[6+q] += (cZ == q) ? vZ : 0.f;
        }
      }
      #pragma unroll
      for (int q = 0; q < 9; ++q) xs[((size_t)b*12 + 3 + q)*512 + d] = a[q];
    }
  } else {
    const int u = blockIdx.x - 8, b = u >> 5, c = u & 31, n0 = c*64;
    __shared__ f32x8 red[12][64];
    __shared__ int scls[64];
    if (tid < 64) {
      float s = 0.f;
      for (int sb_ = 0; sb_ < 8; ++sb_) s += fvp[((size_t)(b*8 + sb_))*NN + n0 + tid];
      scls[tid] = (s > 0.f) ? 0 : ((s < 0.f) ? 1 : 2);
    }
    __syncthreads();
    const int fc = tid & 63, rg = tid >> 6;
    f32x8 sp = {0,0,0,0,0,0,0,0}, sn = sp, sz = sp;
    for (int it = 0; it < 16; ++it) {
      const int nr = rg + it*4;
      const int cls = scls[nr];
      f32x8 hf = b2f8(*(const u16x8*)(xr + ((size_t)b*NN + n0 + nr)*512 + fc*8));
      if (cls == 0) sp += hf; else if (cls == 1) sn += hf; else sz += hf;
    }
    red[0*4+rg][fc] = sp; red[1*4+rg][fc] = sn; red[2*4+rg][fc] = sz;
    __syncthreads();
    if (rg == 0) {
      sp = red[0][fc] + red[1][fc] + red[2][fc] + red[3][fc];
      sn = red[4][fc] + red[5][fc] + red[6][fc] + red[7][fc];
      sz = red[8][fc] + red[9][fc] + red[10][fc] + red[11][fc];
      #pragma unroll
      for (int j = 0; j < 8; ++j) {
        atomicAdd(&xs[((size_t)b*12 + 0)*512 + fc*8 + j], sp[j]);
        atomicAdd(&xs[((size_t)b*12 + 1)*512 + fc*8 + j], sn[j]);
        atomicAdd(&xs[((size_t)b*12 + 2)*512 + fc*8 + j], sz[j]);
      }
    }
  }
}

// ---------- GEMM fused with V-table MFMA.
// MODE 0 = layer1: relu->bf16 g1, PLUS fused g1 class sums (shfl butterfly + strided global atomics)
//                  and sparse set-sum atomics for flagged rows.
// MODE 1 = layer2: +transpose -> out (B,S,N) f32.
template<int MODE>
__global__ __launch_bounds__(256, 2) void k_gemmf(const u16* __restrict__ A, const u16* __restrict__ Bw,
                       const float* __restrict__ bias, const float* __restrict__ sums,
                       const int* __restrict__ meta, const int* __restrict__ rowfl,
                       void* __restrict__ outp, float* __restrict__ osum) {
  __shared__ __align__(16) char SM[33152];
  u16* As  = (u16*)SM;             // 8192 B
  u16* Bs  = (u16*)(SM + 8192);    // 8192 B
  u16* xsb = (u16*)(SM + 16384);   // 16*520*2 = 16640 B
  int* cnt = (int*)(SM + 33088);   // 48 B
  const int tid = threadIdx.x;
  const int w = tid >> 6, l = tid & 63;
  const int wm = w >> 1, wn = w & 1;
  int m0, n0; remap_mn(blockIdx.x, m0, n0);
  const int b = m0 >> 11;

  // prologue: sums f32 [12][512] -> xsb bf16 [16][520]; cnt
  for (int i = tid; i < 12*512; i += 256) {
    const int s = i >> 9, k = i & 511;
    xsb[s*520 + k] = f2b(sums[(size_t)b*12*512 + i]);
  }
  for (int i = tid; i < 4*520; i += 256) xsb[12*520 + i] = 0;
  if (tid < 12) cnt[tid] = meta[b*32 + 18 + tid];

  f32x4 acc[4][4]; f32x4 accV[4];
  #pragma unroll
  for (int i = 0; i < 4; ++i) {
    accV[i] = (f32x4){0.f, 0.f, 0.f, 0.f};
    #pragma unroll
    for (int j = 0; j < 4; ++j) acc[i][j] = (f32x4){0.f, 0.f, 0.f, 0.f};
  }
  const int srow = l >> 2;
  const int sslot = (l & 3) ^ ((l >> 3) & 3);    // pre-swizzled source 16B-slot
  const int skk = sslot * 8;
  const int lr = l & 15;
  const int g = l >> 4;                          // desired global k-slot of the fragment
  const int lkA = ((g ^ ((lr >> 1) & 3)) * 8);   // swizzled LDS read offset (elements)
  const int lk = g * 8;                          // xsb (unswizzled) read offset
  for (int kt = 0; kt < 512; kt += 32) {
    #pragma unroll
    for (int p = 0; p < 2; ++p) {
      const int q = w*2 + p;
      GLOAD16(A  + (size_t)(m0 + q*16 + srow)*512 + kt + skk, As + q*512);
      GLOAD16(Bw + (size_t)(n0 + q*16 + srow)*512 + kt + skk, Bs + q*512);
    }
    __syncthreads();
    bf16x8 af[4], bfr[4];
    #pragma unroll
    for (int i = 0; i < 4; ++i) af[i] = *(const bf16x8*)(As + (wm*64 + i*16 + lr)*32 + lkA);
    #pragma unroll
    for (int j = 0; j < 4; ++j) bfr[j] = *(const bf16x8*)(Bs + (wn*64 + j*16 + lr)*32 + lkA);
    #pragma unroll
    for (int i = 0; i < 4; ++i)
      #pragma unroll
      for (int j = 0; j < 4; ++j)
        acc[i][j] = __builtin_amdgcn_mfma_f32_16x16x32_bf16(bfr[j], af[i], acc[i][j], 0, 0, 0);
    if (wm == 0) {   // V-slice MFMA: D[s][n] for 12 sum-rows
      bf16x8 afx = *(const bf16x8*)(xsb + lr*520 + kt + lk);
      #pragma unroll
      for (int j = 0; j < 4; ++j)
        accV[j] = __builtin_amdgcn_mfma_f32_16x16x32_bf16(afx, bfr[j], accV[j], 0, 0, 0);
    }
    __syncthreads();
  }

  // Vl[12][128] f32 at SM+0 (As region dead)
  float* Vl = (float*)SM;
  if (wm == 0) {
    #pragma unroll
    for (int j = 0; j < 4; ++j) {
      const int c = wn*64 + j*16 + lr;
      const float bv = bias[n0 + c];
      #pragma unroll
      for (int r = 0; r < 4; ++r) {
        const int s = (l >> 4)*4 + r;
        if (s < 12) Vl[s*128 + c] = accV[j][r] + (float)cnt[s] * bv;
      }
    }
  }
  __syncthreads();

  int fl[4]; float rdg[4]; bool cs[4];
  const float* Vb[4];   // per-i class-row base into Vl (LDS pointer, static offsets below)
  #pragma unroll
  for (int i = 0; i < 4; ++i) {
    const int m = m0 + wm*64 + i*16 + lr;
    const int f = rowfl[m];
    fl[i] = f;
    const int cls = f & 3;
    const int bD = (f >> 2) & 1, bA = (f >> 3) & 1, bZ = (f >> 4) & 1;
    const int rb = 3 + cls*3;
    const int c3c = bD*cnt[0] + bA*cnt[1] + bZ*cnt[2];
    const int c2c = cnt[rb] + cnt[rb+1] + cnt[rb+2] - bD*cnt[rb] - bA*cnt[rb+1] - bZ*cnt[rb+2];
    cs[i] = (cls == 0 && bD) || (cls == 1 && bA) || (cls == 2 && bZ);
    float deg = (float)(c3c + c2c) + (cs[i] ? 0.f : 1.f);
    if (deg < 1.f) deg = 1.f;
    rdg[i] = 1.f / deg;
    Vb[i] = Vl + rb*128;
  }

  if (MODE == 0) {
    u16* G = (u16*)outp;
    float* cbin = (float*)(SM + 8192);   // [2][2][4][16][3] = 768 f32 (Bs region dead)
    #pragma unroll
    for (int j = 0; j < 4; ++j) {
      const int dgb = n0 + wn*64 + j*16 + g*4;
      u16x4 o[4];
      #pragma unroll
      for (int r = 0; r < 4; ++r) {
        const int c = wn*64 + j*16 + g*4 + r;
        const float bv = bias[dgb + r];
        const float v0 = Vl[c], v1 = Vl[128 + c], v2 = Vl[256 + c];
        float s0 = 0.f, s1 = 0.f, s2 = 0.f;
        #pragma unroll
        for (int i = 0; i < 4; ++i) {
          const int f = fl[i];
          const float t0 = Vb[i][c], t1 = Vb[i][128 + c], t2 = Vb[i][256 + c];
          float c3 = ((f&4)?v0:0.f) + ((f&8)?v1:0.f) + ((f&16)?v2:0.f);
          float c2 = t0 + t1 + t2
                   - ((f&4)?t0:0.f) - ((f&8)?t1:0.f) - ((f&16)?t2:0.f);
          float val = (c3 + c2) * rdg[i];
          if (!cs[i]) val += (acc[i][j][r] + bv) * rdg[i];
          val = fmaxf(val, 0.f);
          o[i][r] = f2b(val);
          const int cls = f & 3;
          s0 += (cls == 0) ? val : 0.f;
          s1 += (cls == 1) ? val : 0.f;
          s2 += (cls == 2) ? val : 0.f;
          if (f & 0x1C) {  // rare: row in D/A/Z8 set -> sparse set-sum atomics
            if (f & 4)  atomicAdd(&osum[(size_t)(b*12 + 3 + cls)*512 + dgb + r], val);
            if (f & 8)  atomicAdd(&osum[(size_t)(b*12 + 6 + cls)*512 + dgb + r], val);
            if (f & 16) atomicAdd(&osum[(size_t)(b*12 + 9 + cls)*512 + dgb + r], val);
          }
        }
        // butterfly over the 16-lane group (same column c across the group)
        #pragma unroll
        for (int o2 = 1; o2 < 16; o2 <<= 1) {
          s0 += __shfl_xor(s0, o2, 64);
          s1 += __shfl_xor(s1, o2, 64);
          s2 += __shfl_xor(s2, o2, 64);
        }
        if (lr == 0) {
          float* cb = cbin + (((wm*2 + wn)*4 + g)*16 + (j*4 + r))*3;
          cb[0] = s0; cb[1] = s1; cb[2] = s2;
        }
      }
      #pragma unroll
      for (int i = 0; i < 4; ++i)
        *(u16x4*)(G + (size_t)(m0 + wm*64 + i*16 + lr)*512 + dgb) = o[i];
    }
    __syncthreads();
    // combine wm halves; one global atomic per (wn,g,jr,cls): 384 items on 256 threads (strided)
    for (int item = tid; item < 384; item += 256) {
      const int wg = item / 48;        // 0..7 = wn*4 + g
      const int rem = item % 48;
      const int jr = rem / 3, cls = rem % 3;
      const int wnn = wg >> 2, gg = wg & 3;
      const int c = wnn*64 + (jr >> 2)*16 + gg*4 + (jr & 3);
      const float vsum = cbin[(((0*2 + wnn)*4 + gg)*16 + jr)*3 + cls]
                       + cbin[(((1*2 + wnn)*4 + gg)*16 + jr)*3 + cls];
      atomicAdd(&osum[(size_t)(b*12 + cls)*512 + n0 + c], vsum);
    }
  } else {
    float* out = (float*)outp;
    float (*ep)[130] = (float(*)[130])(SM + 8192);   // 32 rows x 130 f32 = 16640 B, after Vl
    const int nloc = m0 & 2047;
    for (int j = 0; j < 4; ++j) {
      #pragma unroll
      for (int r = 0; r < 4; ++r) {
        const int c = wn*64 + j*16 + g*4 + r;
        const float bv = bias[n0 + c];
        const float v0 = Vl[c], v1 = Vl[128 + c], v2 = Vl[256 + c];
        #pragma unroll
        for (int i = 0; i < 4; ++i) {
          const int f = fl[i];
          const float t0 = Vb[i][c], t1 = Vb[i][128 + c], t2 = Vb[i][256 + c];
          float c3 = ((f&4)?v0:0.f) + ((f&8)?v1:0.f) + ((f&16)?v2:0.f);
          float c2 = t0 + t1 + t2
                   - ((f&4)?t0:0.f) - ((f&8)?t1:0.f) - ((f&16)?t2:0.f);
          float val = (c3 + c2) * rdg[i];
          if (!cs[i]) val += (acc[i][j][r] + bv) * rdg[i];
          ep[wn*16 + g*4 + r][wm*64 + i*16 + lr] = val;
        }
      }
      __syncthreads();
      // drain all 32 ep rows: 4 waves x 8 rows x (64 lanes x f32x2 = 128 m)
      #pragma unroll
      for (int rr = 0; rr < 8; ++rr) {
        const int q = w*8 + rr;
        const int s = n0 + (q >> 4)*64 + j*16 + (q & 15);
        float2 v2 = *(const float2*)&ep[q][2*l];
        *(float2*)(out + ((size_t)b*SS + s)*NN + nloc + 2*l) = v2;
      }
      __syncthreads();
    }
  }
}

extern "C" void kernel_launch(void* const* d_in, const int* in_sizes, int n_in,
                              void* d_out, int out_size, void* d_ws, size_t ws_size,
                              hipStream_t stream) {
  const float* x  = (const float*)d_in[0];
  const float* W1 = (const float*)d_in[1];
  const float* b1 = (const float*)d_in[2];
  const float* W2 = (const float*)d_in[3];
  const float* b2 = (const float*)d_in[4];
  float* out = (float*)d_out;
  char* ws = (char*)d_ws;

  float* fvp   = (float*)(ws + 0);           // 512 KB (8*8*2048 f32)
  int*   meta  = (int*)  (ws + 1048576);     // 1 KB
  int*   rowfl = (int*)  (ws + 1049600);     // 64 KB
  float* xs    = (float*)(ws + 1115136);     // 192 KB  [b][12][512] f32
  float* g1s   = (float*)(ws + 1311744);     // 192 KB  (contiguous after xs for zeroing)
  u16*   w1b   = (u16*)  (ws + 1508352);     // 512 KB
  u16*   w2b   = (u16*)  (ws + 2032640);     // 512 KB
  u16*   g1    = (u16*)  (ws + 2556928);     // 16 MB
  u16*   xr    = (u16*)  (ws + 19334144);    // 16 MB

  k_prep<<<4608, 256, 0, stream>>>(x, xr, fvp, W1, W2, w1b, w2b, xs);
  k_tops<<<264, 256, 0, stream>>>(fvp, xr, meta, rowfl, xs);
  k_gemmf<0><<<512, 256, 0, stream>>>(xr, w1b, b1, xs, meta, rowfl, (void*)g1, g1s);
  k_gemmf<1><<<512, 256, 0, stream>>>(g1, w2b, b2, g1s, meta, rowfl, (void*)out, nullptr);
}

// Round 16
// 92.311 us; speedup vs baseline: 10.5973x; 1.0568x over previous
//
#include <hip/hip_runtime.h>
#include <hip/hip_bf16.h>
#include <cstdint>

typedef unsigned short u16;
typedef __bf16 bf16x8 __attribute__((ext_vector_type(8)));
typedef float f32x4 __attribute__((ext_vector_type(4)));
typedef float f32x8 __attribute__((ext_vector_type(8)));
typedef unsigned short u16x4 __attribute__((ext_vector_type(4)));
typedef unsigned short u16x8 __attribute__((ext_vector_type(8)));

#define BB 8
#define SS 512
#define NN 2048
#define HH 512
#define MM (BB*NN)   // 16384

__device__ inline u16 f2b(float f) {
  __hip_bfloat16 h = __float2bfloat16(f);
  return *reinterpret_cast<u16*>(&h);
}
__device__ inline float b2f(u16 u) {
  unsigned x = ((unsigned)u) << 16;
  return __uint_as_float(x);
}
__device__ inline f32x8 b2f8(u16x8 v) {
  f32x8 r;
  #pragma unroll
  for (int k = 0; k < 8; ++k) r[k] = b2f(v[k]);
  return r;
}

#define GLOAD16(g, l) __builtin_amdgcn_global_load_lds( \
    (const __attribute__((address_space(1))) void*)(g), \
    (__attribute__((address_space(3))) void*)(l), 16, 0, 0)

// XCD-aware remap: 4 n-tiles of one m-tile run consecutively on one XCD (A-panel L2 reuse)
__device__ inline void remap_mn(int bid, int& m0, int& n0) {
  const int xcd = bid & 7, k = bid >> 3;   // 512 % 8 == 0 -> bijective
  m0 = (xcd * 16 + (k >> 2)) * 128;
  n0 = (k & 3) * 128;
}

// ---------- P1: transpose x -> xr bf16 (ushort4 writes) + fvp partials (8 per batch); weight cast; zero xs/g1s ----------
__global__ __launch_bounds__(256) void k_prep(const float* __restrict__ x, u16* __restrict__ xr,
                       float* __restrict__ fvp,
                       const float* __restrict__ W1, const float* __restrict__ W2,
                       u16* __restrict__ w1b, u16* __restrict__ w2b,
                       float* __restrict__ xs /* xs+g1s contiguous */) {
  const int u = blockIdx.x;
  const int tid = threadIdx.x;
  if (u < 4096) {
    __shared__ float t[64][33];     // [s_local][n_local]
    __shared__ float ps[8][32];
    const int tx = tid & 31, ty = tid >> 5;
    const int n0 = (u & 63) * 32, st = (u >> 6) & 7, b = u >> 9;
    const int s0 = st * 64;
    float acc = 0.f;
    #pragma unroll
    for (int i = ty; i < 64; i += 8) {
      float w = x[(size_t)b*SS*NN + (size_t)(s0+i)*NN + n0 + tx];
      t[i][tx] = w; acc += w;
    }
    ps[ty][tx] = acc;
    __syncthreads();
    if (ty == 0) {
      float s = 0.f;
      #pragma unroll
      for (int j = 0; j < 8; ++j) s += ps[j][tx];
      fvp[((size_t)(b*8 + st))*NN + n0 + tx] = s;
    }
    const int wtx = tid & 15, wty = tid >> 4;
    #pragma unroll
    for (int j = wty; j < 32; j += 16) {
      ushort4 o;
      o.x = f2b(t[wtx*4+0][j]); o.y = f2b(t[wtx*4+1][j]);
      o.z = f2b(t[wtx*4+2][j]); o.w = f2b(t[wtx*4+3][j]);
      *(ushort4*)(xr + ((size_t)b*NN + n0 + j)*SS + s0 + wtx*4) = o;
    }
    if (u < 96) {   // zero xs + g1s (2 * 8*12*512 f32 = 24576 float4)
      ((float4*)xs)[u*256 + tid] = make_float4(0.f, 0.f, 0.f, 0.f);
    }
  } else {
    const int b2v = u - 4096;                 // 0..511
    const float* Wsrc = (b2v >= 256) ? W2 : W1;
    u16* wb = (b2v >= 256) ? w2b : w1b;
    const int off = (b2v & 255) * 1024;
    float4 v = ((const float4*)(Wsrc + off))[tid];
    ushort4 o; o.x = f2b(v.x); o.y = f2b(v.y); o.z = f2b(v.z); o.w = f2b(v.w);
    *(ushort4*)(wb + off + tid*4) = o;
  }
}

// ---------- P2: topk+setsums (blocks 0..7) || classsums-xr (blocks 8..263) ----------
__global__ __launch_bounds__(256) void k_tops(const float* __restrict__ fvp, const u16* __restrict__ xr,
                       int* __restrict__ meta, int* __restrict__ rowfl, float* __restrict__ xs) {
  const int tid = threadIdx.x;
  if (blockIdx.x < BB) {
    const int b = blockIdx.x;
    __shared__ float v[NN];
    __shared__ unsigned long long wk[8];
    __shared__ unsigned long long winner[2];
    __shared__ int sel[18];
    __shared__ int scnt[12];
    __shared__ int ccnt[12];
    const int wv = tid >> 6, ln = tid & 63;

    float lv[8];
    {
      f32x4 a0 = {0,0,0,0}, a1 = {0,0,0,0};
      for (int sb_ = 0; sb_ < 8; ++sb_) {
        const f32x4* p = (const f32x4*)(fvp + ((size_t)(b*8 + sb_))*NN + tid*8);
        a0 += p[0]; a1 += p[1];
      }
      lv[0]=a0[0]; lv[1]=a0[1]; lv[2]=a0[2]; lv[3]=a0[3];
      lv[4]=a1[0]; lv[5]=a1[1]; lv[6]=a1[2]; lv[7]=a1[3];
    }
    #pragma unroll
    for (int j = 0; j < 8; ++j) v[tid*8+j] = lv[j];

    unsigned long long kD[8], kA[8];
    #pragma unroll
    for (int j = 0; j < 8; ++j) {
      unsigned u = __float_as_uint(lv[j]);
      u = (u & 0x80000000u) ? ~u : (u | 0x80000000u);
      unsigned idx = (unsigned)(tid*8 + j);
      kD[j] = ((unsigned long long)u << 32) | (0xFFFFFFFFu - idx);
      kA[j] = ((unsigned long long)(~u) << 32) | (0xFFFFFFFFu - idx);
    }
    unsigned mskD = 0, mskA = 0;
    for (int r = 0; r < 9; ++r) {
      unsigned long long bD = 0ull, bA = 0ull;
      #pragma unroll
      for (int j = 0; j < 8; ++j) {
        if (!((mskD >> j) & 1) && kD[j] > bD) bD = kD[j];
        if (!((mskA >> j) & 1) && kA[j] > bA) bA = kA[j];
      }
      #pragma unroll
      for (int o = 32; o > 0; o >>= 1) {
        unsigned long long oD = __shfl_xor(bD, o, 64);
        unsigned long long oA = __shfl_xor(bA, o, 64);
        if (oD > bD) bD = oD;
        if (oA > bA) bA = oA;
      }
      if (ln == 0) { wk[wv] = bD; wk[4+wv] = bA; }
      __syncthreads();
      if (tid == 0) {
        unsigned long long mD = wk[0], mA = wk[4];
        #pragma unroll
        for (int q = 1; q < 4; ++q) {
          if (wk[q] > mD) mD = wk[q];
          if (wk[4+q] > mA) mA = wk[4+q];
        }
        winner[0] = mD; winner[1] = mA;
        sel[r]   = (int)(0xFFFFFFFFu - (unsigned)mD);
        sel[9+r] = (int)(0xFFFFFFFFu - (unsigned)mA);
      }
      __syncthreads();
      unsigned iD = 0xFFFFFFFFu - (unsigned)winner[0];
      unsigned iA = 0xFFFFFFFFu - (unsigned)winner[1];
      if ((int)(iD >> 3) == tid) mskD |= 1u << (iD & 7);
      if ((int)(iA >> 3) == tid) mskA |= 1u << (iA & 7);
    }

    int cp = 0, cn = 0, cz = 0;
    #pragma unroll
    for (int j = 0; j < 8; ++j) { cp += (lv[j] > 0.f); cn += (lv[j] < 0.f); cz += (lv[j] == 0.f); }
    #pragma unroll
    for (int o = 32; o > 0; o >>= 1) { cp += __shfl_xor(cp, o, 64); cn += __shfl_xor(cn, o, 64); cz += __shfl_xor(cz, o, 64); }
    if (ln == 0) { ccnt[wv] = cp; ccnt[4+wv] = cn; ccnt[8+wv] = cz; }
    __syncthreads();
    if (tid == 0) {
      int CP = 0, CN = 0, CZ = 0;
      #pragma unroll
      for (int q = 0; q < 4; ++q) { CP += ccnt[q]; CN += ccnt[4+q]; CZ += ccnt[8+q]; }
      scnt[0] = CP; scnt[1] = CN; scnt[2] = CZ;
      for (int t2 = 3; t2 < 12; ++t2) scnt[t2] = 0;
      for (int r = 1; r < 9; ++r) {
        float wD = v[sel[r]];   scnt[3] += (wD > 0.f); scnt[4] += (wD < 0.f); scnt[5] += (wD == 0.f);
        float wA = v[sel[9+r]]; scnt[6] += (wA > 0.f); scnt[7] += (wA < 0.f); scnt[8] += (wA == 0.f);
        float wZ = v[r];        scnt[9] += (wZ > 0.f); scnt[10] += (wZ < 0.f); scnt[11] += (wZ == 0.f);
      }
    }
    __syncthreads();
    #pragma unroll
    for (int j = 0; j < 8; ++j) {
      const int i = tid*8 + j;
      float w = lv[j];
      int cls = (w > 0.f) ? 0 : ((w < 0.f) ? 1 : 2);
      int mD = 0, mA = 0;
      #pragma unroll
      for (int r = 1; r < 9; ++r) { mD |= (sel[r] == i); mA |= (sel[9+r] == i); }
      int mZ8 = (i >= 1 && i <= 8);
      rowfl[b*NN + i] = cls | (mD << 2) | (mA << 3) | (mZ8 << 4);
    }
    if (tid < 18) meta[b*32 + tid] = sel[tid];
    if (tid >= 18 && tid < 30) meta[b*32 + tid] = scnt[tid - 18];
    __syncthreads();
    // set sums of xr over D/A/Z8 rows (single-writer, rows 3..11 of xs) — static-indexed accumulators
    #pragma unroll
    for (int half = 0; half < 2; ++half) {
      const int d = tid + half*256;
      float a[9];
      #pragma unroll
      for (int q = 0; q < 9; ++q) a[q] = 0.f;
      for (int r = 1; r < 9; ++r) {
        int iD = sel[r];   float wD = v[iD]; int cD = (wD>0.f)?0:((wD<0.f)?1:2);
        float vD = b2f(xr[((size_t)b*NN + iD)*512 + d]);
        int iA = sel[9+r]; float wA = v[iA]; int cA = (wA>0.f)?0:((wA<0.f)?1:2);
        float vA = b2f(xr[((size_t)b*NN + iA)*512 + d]);
        float wZ = v[r];   int cZ = (wZ>0.f)?0:((wZ<0.f)?1:2);
        float vZ = b2f(xr[((size_t)b*NN + r)*512 + d]);
        #pragma unroll
        for (int q = 0; q < 3; ++q) {
          a[q]   += (cD == q) ? vD : 0.f;
          a[3+q] += (cA == q) ? vA : 0.f;
          a[6+q] += (cZ == q) ? vZ : 0.f;
        }
      }
      #pragma unroll
      for (int q = 0; q < 9; ++q) xs[((size_t)b*12 + 3 + q)*512 + d] = a[q];
    }
  } else {
    const int u = blockIdx.x - 8, b = u >> 5, c = u & 31, n0 = c*64;
    __shared__ f32x8 red[12][64];
    __shared__ int scls[64];
    if (tid < 64) {
      float s = 0.f;
      for (int sb_ = 0; sb_ < 8; ++sb_) s += fvp[((size_t)(b*8 + sb_))*NN + n0 + tid];
      scls[tid] = (s > 0.f) ? 0 : ((s < 0.f) ? 1 : 2);
    }
    __syncthreads();
    const int fc = tid & 63, rg = tid >> 6;
    f32x8 sp = {0,0,0,0,0,0,0,0}, sn = sp, sz = sp;
    for (int it = 0; it < 16; ++it) {
      const int nr = rg + it*4;
      const int cls = scls[nr];
      f32x8 hf = b2f8(*(const u16x8*)(xr + ((size_t)b*NN + n0 + nr)*512 + fc*8));
      if (cls == 0) sp += hf; else if (cls == 1) sn += hf; else sz += hf;
    }
    red[0*4+rg][fc] = sp; red[1*4+rg][fc] = sn; red[2*4+rg][fc] = sz;
    __syncthreads();
    if (rg == 0) {
      sp = red[0][fc] + red[1][fc] + red[2][fc] + red[3][fc];
      sn = red[4][fc] + red[5][fc] + red[6][fc] + red[7][fc];
      sz = red[8][fc] + red[9][fc] + red[10][fc] + red[11][fc];
      #pragma unroll
      for (int j = 0; j < 8; ++j) {
        atomicAdd(&xs[((size_t)b*12 + 0)*512 + fc*8 + j], sp[j]);
        atomicAdd(&xs[((size_t)b*12 + 1)*512 + fc*8 + j], sn[j]);
        atomicAdd(&xs[((size_t)b*12 + 2)*512 + fc*8 + j], sz[j]);
      }
    }
  }
}

// ---------- GEMM fused with V-table MFMA, BK=64 (8 K-steps, halved barrier drains).
// LDS layout: As/Bs [128 rows][8 slots of 16B], slot XOR-swizzled by (row&7):
//   stage: linear LDS dest (uniform base + lane*16B), pre-swizzled GLOBAL slot (l&7)^((l>>3)&7)
//   read : lin_slot = want ^ (row&7)
// MODE 0 = layer1: relu->bf16 g1 + fused g1 class sums + sparse set-sum atomics.
// MODE 1 = layer2: +transpose -> out (B,S,N) f32.
template<int MODE>
__global__ __launch_bounds__(256, 2) void k_gemmf(const u16* __restrict__ A, const u16* __restrict__ Bw,
                       const float* __restrict__ bias, const float* __restrict__ sums,
                       const int* __restrict__ meta, const int* __restrict__ rowfl,
                       void* __restrict__ outp, float* __restrict__ osum) {
  __shared__ __align__(16) char SM[49472];
  u16* As  = (u16*)SM;              // 16384 B  [128][64]
  u16* Bs  = (u16*)(SM + 16384);    // 16384 B  [128][64]
  u16* xsb = (u16*)(SM + 32768);    // 16*520*2 = 16640 B
  int* cnt = (int*)(SM + 49408);    // 48 B
  const int tid = threadIdx.x;
  const int w = tid >> 6, l = tid & 63;
  const int wm = w >> 1, wn = w & 1;
  int m0, n0; remap_mn(blockIdx.x, m0, n0);
  const int b = m0 >> 11;

  // prologue: sums f32 [12][512] -> xsb bf16 [16][520]; cnt
  for (int i = tid; i < 12*512; i += 256) {
    const int s = i >> 9, k = i & 511;
    xsb[s*520 + k] = f2b(sums[(size_t)b*12*512 + i]);
  }
  for (int i = tid; i < 4*520; i += 256) xsb[12*520 + i] = 0;
  if (tid < 12) cnt[tid] = meta[b*32 + 18 + tid];

  f32x4 acc[4][4]; f32x4 accV[4];
  #pragma unroll
  for (int i = 0; i < 4; ++i) {
    accV[i] = (f32x4){0.f, 0.f, 0.f, 0.f};
    #pragma unroll
    for (int j = 0; j < 4; ++j) acc[i][j] = (f32x4){0.f, 0.f, 0.f, 0.f};
  }
  const int lr = l & 15;
  const int g4 = l >> 4;                         // 0..3: k-16B-slot within a 32-slice
  const int srow8 = l >> 3;                      // staging: row-within-8-group
  const int gslot = (l & 7) ^ (srow8 & 7);       // pre-swizzled global 16B-slot (0..7)
  for (int kt = 0; kt < 512; kt += 64) {
    #pragma unroll
    for (int p = 0; p < 4; ++p) {
      const int rbase = w*32 + p*8;              // uniform per (w,p)
      const int row = rbase + srow8;             // lane's row (staging)
      GLOAD16(A  + (size_t)(m0 + row)*512 + kt + gslot*8, As + rbase*64);
      GLOAD16(Bw + (size_t)(n0 + row)*512 + kt + gslot*8, Bs + rbase*64);
    }
    __syncthreads();
    #pragma unroll
    for (int ks = 0; ks < 2; ++ks) {
      bf16x8 af[4], bfr[4];
      #pragma unroll
      for (int i = 0; i < 4; ++i) {
        const int r = wm*64 + i*16 + lr;
        const int lin = (ks*4 + g4) ^ (lr & 7);
        af[i] = *(const bf16x8*)(As + r*64 + lin*8);
      }
      #pragma unroll
      for (int j = 0; j < 4; ++j) {
        const int r = wn*64 + j*16 + lr;
        const int lin = (ks*4 + g4) ^ (lr & 7);
        bfr[j] = *(const bf16x8*)(Bs + r*64 + lin*8);
      }
      #pragma unroll
      for (int i = 0; i < 4; ++i)
        #pragma unroll
        for (int j = 0; j < 4; ++j)
          acc[i][j] = __builtin_amdgcn_mfma_f32_16x16x32_bf16(bfr[j], af[i], acc[i][j], 0, 0, 0);
      if (wm == 0) {   // V-slice MFMA: D[s][n] for 12 sum-rows
        bf16x8 afx = *(const bf16x8*)(xsb + lr*520 + kt + ks*32 + g4*8);
        #pragma unroll
        for (int j = 0; j < 4; ++j)
          accV[j] = __builtin_amdgcn_mfma_f32_16x16x32_bf16(afx, bfr[j], accV[j], 0, 0, 0);
      }
    }
    __syncthreads();
  }

  // Vl[12][128] f32 at SM+0 (As region dead)
  float* Vl = (float*)SM;
  if (wm == 0) {
    #pragma unroll
    for (int j = 0; j < 4; ++j) {
      const int c = wn*64 + j*16 + lr;
      const float bv = bias[n0 + c];
      #pragma unroll
      for (int r = 0; r < 4; ++r) {
        const int s = g4*4 + r;
        if (s < 12) Vl[s*128 + c] = accV[j][r] + (float)cnt[s] * bv;
      }
    }
  }
  __syncthreads();

  int fl[4]; float rdg[4]; bool cs[4];
  const float* Vb[4];   // per-i class-row base into Vl (LDS pointer, static offsets below)
  #pragma unroll
  for (int i = 0; i < 4; ++i) {
    const int m = m0 + wm*64 + i*16 + lr;
    const int f = rowfl[m];
    fl[i] = f;
    const int cls = f & 3;
    const int bD = (f >> 2) & 1, bA = (f >> 3) & 1, bZ = (f >> 4) & 1;
    const int rb = 3 + cls*3;
    const int c3c = bD*cnt[0] + bA*cnt[1] + bZ*cnt[2];
    const int c2c = cnt[rb] + cnt[rb+1] + cnt[rb+2] - bD*cnt[rb] - bA*cnt[rb+1] - bZ*cnt[rb+2];
    cs[i] = (cls == 0 && bD) || (cls == 1 && bA) || (cls == 2 && bZ);
    float deg = (float)(c3c + c2c) + (cs[i] ? 0.f : 1.f);
    if (deg < 1.f) deg = 1.f;
    rdg[i] = 1.f / deg;
    Vb[i] = Vl + rb*128;
  }

  if (MODE == 0) {
    u16* G = (u16*)outp;
    float* cbin = (float*)(SM + 8192);   // [2][2][4][16][3] = 768 f32 (dead As region, after Vl's 6KB)
    #pragma unroll
    for (int j = 0; j < 4; ++j) {
      const int dgb = n0 + wn*64 + j*16 + g4*4;
      u16x4 o[4];
      #pragma unroll
      for (int r = 0; r < 4; ++r) {
        const int c = wn*64 + j*16 + g4*4 + r;
        const float bv = bias[dgb + r];
        const float v0 = Vl[c], v1 = Vl[128 + c], v2 = Vl[256 + c];
        float s0 = 0.f, s1 = 0.f, s2 = 0.f;
        #pragma unroll
        for (int i = 0; i < 4; ++i) {
          const int f = fl[i];
          const float t0 = Vb[i][c], t1 = Vb[i][128 + c], t2 = Vb[i][256 + c];
          float c3 = ((f&4)?v0:0.f) + ((f&8)?v1:0.f) + ((f&16)?v2:0.f);
          float c2 = t0 + t1 + t2
                   - ((f&4)?t0:0.f) - ((f&8)?t1:0.f) - ((f&16)?t2:0.f);
          float val = (c3 + c2) * rdg[i];
          if (!cs[i]) val += (acc[i][j][r] + bv) * rdg[i];
          val = fmaxf(val, 0.f);
          o[i][r] = f2b(val);
          const int cls = f & 3;
          s0 += (cls == 0) ? val : 0.f;
          s1 += (cls == 1) ? val : 0.f;
          s2 += (cls == 2) ? val : 0.f;
          if (f & 0x1C) {  // rare: row in D/A/Z8 set -> sparse set-sum atomics
            if (f & 4)  atomicAdd(&osum[(size_t)(b*12 + 3 + cls)*512 + dgb + r], val);
            if (f & 8)  atomicAdd(&osum[(size_t)(b*12 + 6 + cls)*512 + dgb + r], val);
            if (f & 16) atomicAdd(&osum[(size_t)(b*12 + 9 + cls)*512 + dgb + r], val);
          }
        }
        // butterfly over the 16-lane group (same column c across the group)
        #pragma unroll
        for (int o2 = 1; o2 < 16; o2 <<= 1) {
          s0 += __shfl_xor(s0, o2, 64);
          s1 += __shfl_xor(s1, o2, 64);
          s2 += __shfl_xor(s2, o2, 64);
        }
        if (lr == 0) {
          float* cb = cbin + (((wm*2 + wn)*4 + g4)*16 + (j*4 + r))*3;
          cb[0] = s0; cb[1] = s1; cb[2] = s2;
        }
      }
      #pragma unroll
      for (int i = 0; i < 4; ++i)
        *(u16x4*)(G + (size_t)(m0 + wm*64 + i*16 + lr)*512 + dgb) = o[i];
    }
    __syncthreads();
    // combine wm halves; one global atomic per (wn,g4,jr,cls): 384 items on 256 threads (strided)
    for (int item = tid; item < 384; item += 256) {
      const int wg = item / 48;        // 0..7 = wn*4 + g4
      const int rem = item % 48;
      const int jr = rem / 3, cls = rem % 3;
      const int wnn = wg >> 2, gg = wg & 3;
      const int c = wnn*64 + (jr >> 2)*16 + gg*4 + (jr & 3);
      const float vsum = cbin[(((0*2 + wnn)*4 + gg)*16 + jr)*3 + cls]
                       + cbin[(((1*2 + wnn)*4 + gg)*16 + jr)*3 + cls];
      atomicAdd(&osum[(size_t)(b*12 + cls)*512 + n0 + c], vsum);
    }
  } else {
    float* out = (float*)outp;
    float (*ep)[130] = (float(*)[130])(SM + 8192);   // 32 rows x 130 f32 = 16640 B (dead As/Bs region)
    const int nloc = m0 & 2047;
    for (int j = 0; j < 4; ++j) {
      #pragma unroll
      for (int r = 0; r < 4; ++r) {
        const int c = wn*64 + j*16 + g4*4 + r;
        const float bv = bias[n0 + c];
        const float v0 = Vl[c], v1 = Vl[128 + c], v2 = Vl[256 + c];
        #pragma unroll
        for (int i = 0; i < 4; ++i) {
          const int f = fl[i];
          const float t0 = Vb[i][c], t1 = Vb[i][128 + c], t2 = Vb[i][256 + c];
          float c3 = ((f&4)?v0:0.f) + ((f&8)?v1:0.f) + ((f&16)?v2:0.f);
          float c2 = t0 + t1 + t2
                   - ((f&4)?t0:0.f) - ((f&8)?t1:0.f) - ((f&16)?t2:0.f);
          float val = (c3 + c2) * rdg[i];
          if (!cs[i]) val += (acc[i][j][r] + bv) * rdg[i];
          ep[wn*16 + g4*4 + r][wm*64 + i*16 + lr] = val;
        }
      }
      __syncthreads();
      // drain all 32 ep rows: 4 waves x 8 rows x (64 lanes x f32x2 = 128 m)
      #pragma unroll
      for (int rr = 0; rr < 8; ++rr) {
        const int q = w*8 + rr;
        const int s = n0 + (q >> 4)*64 + j*16 + (q & 15);
        float2 v2 = *(const float2*)&ep[q][2*l];
        *(float2*)(out + ((size_t)b*SS + s)*NN + nloc + 2*l) = v2;
      }
      __syncthreads();
    }
  }
}

extern "C" void kernel_launch(void* const* d_in, const int* in_sizes, int n_in,
                              void* d_out, int out_size, void* d_ws, size_t ws_size,
                              hipStream_t stream) {
  const float* x  = (const float*)d_in[0];
  const float* W1 = (const float*)d_in[1];
  const float* b1 = (const float*)d_in[2];
  const float* W2 = (const float*)d_in[3];
  const float* b2 = (const float*)d_in[4];
  float* out = (float*)d_out;
  char* ws = (char*)d_ws;

  float* fvp   = (float*)(ws + 0);           // 512 KB (8*8*2048 f32)
  int*   meta  = (int*)  (ws + 1048576);     // 1 KB
  int*   rowfl = (int*)  (ws + 1049600);     // 64 KB
  float* xs    = (float*)(ws + 1115136);     // 192 KB  [b][12][512] f32
  float* g1s   = (float*)(ws + 1311744);     // 192 KB  (contiguous after xs for zeroing)
  u16*   w1b   = (u16*)  (ws + 1508352);     // 512 KB
  u16*   w2b   = (u16*)  (ws + 2032640);     // 512 KB
  u16*   g1    = (u16*)  (ws + 2556928);     // 16 MB
  u16*   xr    = (u16*)  (ws + 19334144);    // 16 MB

  k_prep<<<4608, 256, 0, stream>>>(x, xr, fvp, W1, W2, w1b, w2b, xs);
  k_tops<<<264, 256, 0, stream>>>(fvp, xr, meta, rowfl, xs);
  k_gemmf<0><<<512, 256, 0, stream>>>(xr, w1b, b1, xs, meta, rowfl, (void*)g1, g1s);
  k_gemmf<1><<<512, 256, 0, stream>>>(g1, w2b, b2, g1s, meta, rowfl, (void*)out, nullptr);
}

// Round 17
// 92.211 us; speedup vs baseline: 10.6088x; 1.0011x over previous
//
#include <hip/hip_runtime.h>
#include <hip/hip_bf16.h>
#include <cstdint>

typedef unsigned short u16;
typedef __bf16 bf16x8 __attribute__((ext_vector_type(8)));
typedef float f32x4 __attribute__((ext_vector_type(4)));
typedef float f32x8 __attribute__((ext_vector_type(8)));
typedef unsigned short u16x4 __attribute__((ext_vector_type(4)));
typedef unsigned short u16x8 __attribute__((ext_vector_type(8)));

#define BB 8
#define SS 512
#define NN 2048
#define HH 512
#define MM (BB*NN)   // 16384

__device__ inline u16 f2b(float f) {
  __hip_bfloat16 h = __float2bfloat16(f);
  return *reinterpret_cast<u16*>(&h);
}
__device__ inline float b2f(u16 u) {
  unsigned x = ((unsigned)u) << 16;
  return __uint_as_float(x);
}
__device__ inline f32x8 b2f8(u16x8 v) {
  f32x8 r;
  #pragma unroll
  for (int k = 0; k < 8; ++k) r[k] = b2f(v[k]);
  return r;
}

#define GLOAD16(g, l) __builtin_amdgcn_global_load_lds( \
    (const __attribute__((address_space(1))) void*)(g), \
    (__attribute__((address_space(3))) void*)(l), 16, 0, 0)

// XCD-aware remap: 4 n-tiles of one m-tile run consecutively on one XCD (A-panel L2 reuse)
__device__ inline void remap_mn(int bid, int& m0, int& n0) {
  const int xcd = bid & 7, k = bid >> 3;   // 512 % 8 == 0 -> bijective
  m0 = (xcd * 16 + (k >> 2)) * 128;
  n0 = (k & 3) * 128;
}

// ---------- P1: transpose x -> xr bf16 (ushort4 writes) + fvp partials (8 per batch); weight cast; zero xs/g1s ----------
__global__ __launch_bounds__(256) void k_prep(const float* __restrict__ x, u16* __restrict__ xr,
                       float* __restrict__ fvp,
                       const float* __restrict__ W1, const float* __restrict__ W2,
                       u16* __restrict__ w1b, u16* __restrict__ w2b,
                       float* __restrict__ xs /* xs+g1s contiguous */) {
  const int u = blockIdx.x;
  const int tid = threadIdx.x;
  if (u < 4096) {
    __shared__ float t[64][33];     // [s_local][n_local]
    __shared__ float ps[8][32];
    const int tx = tid & 31, ty = tid >> 5;
    const int n0 = (u & 63) * 32, st = (u >> 6) & 7, b = u >> 9;
    const int s0 = st * 64;
    float acc = 0.f;
    #pragma unroll
    for (int i = ty; i < 64; i += 8) {
      float w = x[(size_t)b*SS*NN + (size_t)(s0+i)*NN + n0 + tx];
      t[i][tx] = w; acc += w;
    }
    ps[ty][tx] = acc;
    __syncthreads();
    if (ty == 0) {
      float s = 0.f;
      #pragma unroll
      for (int j = 0; j < 8; ++j) s += ps[j][tx];
      fvp[((size_t)(b*8 + st))*NN + n0 + tx] = s;
    }
    const int wtx = tid & 15, wty = tid >> 4;
    #pragma unroll
    for (int j = wty; j < 32; j += 16) {
      ushort4 o;
      o.x = f2b(t[wtx*4+0][j]); o.y = f2b(t[wtx*4+1][j]);
      o.z = f2b(t[wtx*4+2][j]); o.w = f2b(t[wtx*4+3][j]);
      *(ushort4*)(xr + ((size_t)b*NN + n0 + j)*SS + s0 + wtx*4) = o;
    }
    if (u < 96) {   // zero xs + g1s (2 * 8*12*512 f32 = 24576 float4)
      ((float4*)xs)[u*256 + tid] = make_float4(0.f, 0.f, 0.f, 0.f);
    }
  } else {
    const int b2v = u - 4096;                 // 0..511
    const float* Wsrc = (b2v >= 256) ? W2 : W1;
    u16* wb = (b2v >= 256) ? w2b : w1b;
    const int off = (b2v & 255) * 1024;
    float4 v = ((const float4*)(Wsrc + off))[tid];
    ushort4 o; o.x = f2b(v.x); o.y = f2b(v.y); o.z = f2b(v.z); o.w = f2b(v.w);
    *(ushort4*)(wb + off + tid*4) = o;
  }
}

// ---------- P2: topk+setsums (blocks 0..7) || classsums-xr (blocks 8..263) ----------
__global__ __launch_bounds__(256) void k_tops(const float* __restrict__ fvp, const u16* __restrict__ xr,
                       int* __restrict__ meta, int* __restrict__ rowfl, float* __restrict__ xs) {
  const int tid = threadIdx.x;
  if (blockIdx.x < BB) {
    const int b = blockIdx.x;
    __shared__ float v[NN];
    __shared__ unsigned long long wk[8];
    __shared__ unsigned long long winner[2];
    __shared__ int sel[18];
    __shared__ int scnt[12];
    __shared__ int ccnt[12];
    const int wv = tid >> 6, ln = tid & 63;

    float lv[8];
    {
      f32x4 a0 = {0,0,0,0}, a1 = {0,0,0,0};
      for (int sb_ = 0; sb_ < 8; ++sb_) {
        const f32x4* p = (const f32x4*)(fvp + ((size_t)(b*8 + sb_))*NN + tid*8);
        a0 += p[0]; a1 += p[1];
      }
      lv[0]=a0[0]; lv[1]=a0[1]; lv[2]=a0[2]; lv[3]=a0[3];
      lv[4]=a1[0]; lv[5]=a1[1]; lv[6]=a1[2]; lv[7]=a1[3];
    }
    #pragma unroll
    for (int j = 0; j < 8; ++j) v[tid*8+j] = lv[j];

    unsigned long long kD[8], kA[8];
    #pragma unroll
    for (int j = 0; j < 8; ++j) {
      unsigned u = __float_as_uint(lv[j]);
      u = (u & 0x80000000u) ? ~u : (u | 0x80000000u);
      unsigned idx = (unsigned)(tid*8 + j);
      kD[j] = ((unsigned long long)u << 32) | (0xFFFFFFFFu - idx);
      kA[j] = ((unsigned long long)(~u) << 32) | (0xFFFFFFFFu - idx);
    }
    unsigned mskD = 0, mskA = 0;
    for (int r = 0; r < 9; ++r) {
      unsigned long long bD = 0ull, bA = 0ull;
      #pragma unroll
      for (int j = 0; j < 8; ++j) {
        if (!((mskD >> j) & 1) && kD[j] > bD) bD = kD[j];
        if (!((mskA >> j) & 1) && kA[j] > bA) bA = kA[j];
      }
      #pragma unroll
      for (int o = 32; o > 0; o >>= 1) {
        unsigned long long oD = __shfl_xor(bD, o, 64);
        unsigned long long oA = __shfl_xor(bA, o, 64);
        if (oD > bD) bD = oD;
        if (oA > bA) bA = oA;
      }
      if (ln == 0) { wk[wv] = bD; wk[4+wv] = bA; }
      __syncthreads();
      if (tid == 0) {
        unsigned long long mD = wk[0], mA = wk[4];
        #pragma unroll
        for (int q = 1; q < 4; ++q) {
          if (wk[q] > mD) mD = wk[q];
          if (wk[4+q] > mA) mA = wk[4+q];
        }
        winner[0] = mD; winner[1] = mA;
        sel[r]   = (int)(0xFFFFFFFFu - (unsigned)mD);
        sel[9+r] = (int)(0xFFFFFFFFu - (unsigned)mA);
      }
      __syncthreads();
      unsigned iD = 0xFFFFFFFFu - (unsigned)winner[0];
      unsigned iA = 0xFFFFFFFFu - (unsigned)winner[1];
      if ((int)(iD >> 3) == tid) mskD |= 1u << (iD & 7);
      if ((int)(iA >> 3) == tid) mskA |= 1u << (iA & 7);
    }

    int cp = 0, cn = 0, cz = 0;
    #pragma unroll
    for (int j = 0; j < 8; ++j) { cp += (lv[j] > 0.f); cn += (lv[j] < 0.f); cz += (lv[j] == 0.f); }
    #pragma unroll
    for (int o = 32; o > 0; o >>= 1) { cp += __shfl_xor(cp, o, 64); cn += __shfl_xor(cn, o, 64); cz += __shfl_xor(cz, o, 64); }
    if (ln == 0) { ccnt[wv] = cp; ccnt[4+wv] = cn; ccnt[8+wv] = cz; }
    __syncthreads();
    if (tid == 0) {
      int CP = 0, CN = 0, CZ = 0;
      #pragma unroll
      for (int q = 0; q < 4; ++q) { CP += ccnt[q]; CN += ccnt[4+q]; CZ += ccnt[8+q]; }
      scnt[0] = CP; scnt[1] = CN; scnt[2] = CZ;
      for (int t2 = 3; t2 < 12; ++t2) scnt[t2] = 0;
      for (int r = 1; r < 9; ++r) {
        float wD = v[sel[r]];   scnt[3] += (wD > 0.f); scnt[4] += (wD < 0.f); scnt[5] += (wD == 0.f);
        float wA = v[sel[9+r]]; scnt[6] += (wA > 0.f); scnt[7] += (wA < 0.f); scnt[8] += (wA == 0.f);
        float wZ = v[r];        scnt[9] += (wZ > 0.f); scnt[10] += (wZ < 0.f); scnt[11] += (wZ == 0.f);
      }
    }
    __syncthreads();
    #pragma unroll
    for (int j = 0; j < 8; ++j) {
      const int i = tid*8 + j;
      float w = lv[j];
      int cls = (w > 0.f) ? 0 : ((w < 0.f) ? 1 : 2);
      int mD = 0, mA = 0;
      #pragma unroll
      for (int r = 1; r < 9; ++r) { mD |= (sel[r] == i); mA |= (sel[9+r] == i); }
      int mZ8 = (i >= 1 && i <= 8);
      rowfl[b*NN + i] = cls | (mD << 2) | (mA << 3) | (mZ8 << 4);
    }
    if (tid < 18) meta[b*32 + tid] = sel[tid];
    if (tid >= 18 && tid < 30) meta[b*32 + tid] = scnt[tid - 18];
    __syncthreads();
    // set sums of xr over D/A/Z8 rows (single-writer, rows 3..11 of xs) — static-indexed accumulators
    #pragma unroll
    for (int half = 0; half < 2; ++half) {
      const int d = tid + half*256;
      float a[9];
      #pragma unroll
      for (int q = 0; q < 9; ++q) a[q] = 0.f;
      for (int r = 1; r < 9; ++r) {
        int iD = sel[r];   float wD = v[iD]; int cD = (wD>0.f)?0:((wD<0.f)?1:2);
        float vD = b2f(xr[((size_t)b*NN + iD)*512 + d]);
        int iA = sel[9+r]; float wA = v[iA]; int cA = (wA>0.f)?0:((wA<0.f)?1:2);
        float vA = b2f(xr[((size_t)b*NN + iA)*512 + d]);
        float wZ = v[r];   int cZ = (wZ>0.f)?0:((wZ<0.f)?1:2);
        float vZ = b2f(xr[((size_t)b*NN + r)*512 + d]);
        #pragma unroll
        for (int q = 0; q < 3; ++q) {
          a[q]   += (cD == q) ? vD : 0.f;
          a[3+q] += (cA == q) ? vA : 0.f;
          a[6+q] += (cZ == q) ? vZ : 0.f;
        }
      }
      #pragma unroll
      for (int q = 0; q < 9; ++q) xs[((size_t)b*12 + 3 + q)*512 + d] = a[q];
    }
  } else {
    const int u = blockIdx.x - 8, b = u >> 5, c = u & 31, n0 = c*64;
    __shared__ f32x8 red[12][64];
    __shared__ int scls[64];
    if (tid < 64) {
      float s = 0.f;
      for (int sb_ = 0; sb_ < 8; ++sb_) s += fvp[((size_t)(b*8 + sb_))*NN + n0 + tid];
      scls[tid] = (s > 0.f) ? 0 : ((s < 0.f) ? 1 : 2);
    }
    __syncthreads();
    const int fc = tid & 63, rg = tid >> 6;
    f32x8 sp = {0,0,0,0,0,0,0,0}, sn = sp, sz = sp;
    for (int it = 0; it < 16; ++it) {
      const int nr = rg + it*4;
      const int cls = scls[nr];
      f32x8 hf = b2f8(*(const u16x8*)(xr + ((size_t)b*NN + n0 + nr)*512 + fc*8));
      if (cls == 0) sp += hf; else if (cls == 1) sn += hf; else sz += hf;
    }
    red[0*4+rg][fc] = sp; red[1*4+rg][fc] = sn; red[2*4+rg][fc] = sz;
    __syncthreads();
    if (rg == 0) {
      sp = red[0][fc] + red[1][fc] + red[2][fc] + red[3][fc];
      sn = red[4][fc] + red[5][fc] + red[6][fc] + red[7][fc];
      sz = red[8][fc] + red[9][fc] + red[10][fc] + red[11][fc];
      #pragma unroll
      for (int j = 0; j < 8; ++j) {
        atomicAdd(&xs[((size_t)b*12 + 0)*512 + fc*8 + j], sp[j]);
        atomicAdd(&xs[((size_t)b*12 + 1)*512 + fc*8 + j], sn[j]);
        atomicAdd(&xs[((size_t)b*12 + 2)*512 + fc*8 + j], sz[j]);
      }
    }
  }
}

// ---------- GEMM fused with V-table MFMA, BK=64, double-buffered LDS with counted vmcnt
// (T3/T4 minimum-2-phase: next-tile global_load_lds stays in flight across the barrier).
// LDS: As0/Bs0/As1/Bs1 16KB each; xsb 12 rows (lanes lr>=12 read remapped row, output discarded by s<12 guard).
// MODE 0 = layer1: relu->bf16 g1 + fused g1 class sums + sparse set-sum atomics.
// MODE 1 = layer2: +transpose -> out (B,S,N) f32.
template<int MODE>
__global__ __launch_bounds__(256, 2) void k_gemmf(const u16* __restrict__ A, const u16* __restrict__ Bw,
                       const float* __restrict__ bias, const float* __restrict__ sums,
                       const int* __restrict__ meta, const int* __restrict__ rowfl,
                       void* __restrict__ outp, float* __restrict__ osum) {
  __shared__ __align__(16) char SM[78080];
  u16* xsb = (u16*)(SM + 65536);    // 12*520*2 = 12480 B
  int* cnt = (int*)(SM + 78016);    // 48 B
  const int tid = threadIdx.x;
  const int w = tid >> 6, l = tid & 63;
  const int wm = w >> 1, wn = w & 1;
  int m0, n0; remap_mn(blockIdx.x, m0, n0);
  const int b = m0 >> 11;

  // prologue: sums f32 [12][512] -> xsb bf16 [12][520]; cnt
  for (int i = tid; i < 12*512; i += 256) {
    const int s = i >> 9, k = i & 511;
    xsb[s*520 + k] = f2b(sums[(size_t)b*12*512 + i]);
  }
  if (tid < 12) cnt[tid] = meta[b*32 + 18 + tid];

  f32x4 acc[4][4]; f32x4 accV[4];
  #pragma unroll
  for (int i = 0; i < 4; ++i) {
    accV[i] = (f32x4){0.f, 0.f, 0.f, 0.f};
    #pragma unroll
    for (int j = 0; j < 4; ++j) acc[i][j] = (f32x4){0.f, 0.f, 0.f, 0.f};
  }
  const int lr = l & 15;
  const int xrow = (lr < 12) ? lr : (lr - 12);   // xsb row remap (rows 12..15 discarded later)
  const int g4 = l >> 4;                         // 0..3: k-16B-slot within a 32-slice
  const int srow8 = l >> 3;                      // staging: row-within-8-group
  const int gslot = (l & 7) ^ (srow8 & 7);       // pre-swizzled global 16B-slot (0..7)

#define STAGE_T(Ad, Bd, ktq) { \
    _Pragma("unroll") \
    for (int p = 0; p < 4; ++p) { \
      const int rbase = w*32 + p*8; \
      const int row = rbase + srow8; \
      GLOAD16(A  + (size_t)(m0 + row)*512 + (ktq) + gslot*8, (Ad) + rbase*64); \
      GLOAD16(Bw + (size_t)(n0 + row)*512 + (ktq) + gslot*8, (Bd) + rbase*64); \
    } }

  {
    u16* As0 = (u16*)SM;
    u16* Bs0 = (u16*)(SM + 16384);
    STAGE_T(As0, Bs0, 0);
  }
  #pragma unroll
  for (int t = 0; t < 8; ++t) {
    u16* Ac = (u16*)(SM + ((t & 1) ? 32768 : 0));
    u16* Bc = Ac + 8192;                         // +16384 B
    u16* An = (u16*)(SM + ((t & 1) ? 0 : 32768));
    u16* Bn = An + 8192;
    if (t < 7) {
      STAGE_T(An, Bn, (t+1)*64);
      asm volatile("s_waitcnt vmcnt(8)" ::: "memory");
    } else {
      asm volatile("s_waitcnt vmcnt(0)" ::: "memory");
    }
    __builtin_amdgcn_sched_barrier(0);
    __builtin_amdgcn_s_barrier();
    __builtin_amdgcn_sched_barrier(0);
    const int kt = t * 64;
    #pragma unroll
    for (int ks = 0; ks < 2; ++ks) {
      bf16x8 af[4], bfr[4];
      #pragma unroll
      for (int i = 0; i < 4; ++i) {
        const int r = wm*64 + i*16 + lr;
        const int lin = (ks*4 + g4) ^ (lr & 7);
        af[i] = *(const bf16x8*)(Ac + r*64 + lin*8);
      }
      #pragma unroll
      for (int j = 0; j < 4; ++j) {
        const int r = wn*64 + j*16 + lr;
        const int lin = (ks*4 + g4) ^ (lr & 7);
        bfr[j] = *(const bf16x8*)(Bc + r*64 + lin*8);
      }
      #pragma unroll
      for (int i = 0; i < 4; ++i)
        #pragma unroll
        for (int j = 0; j < 4; ++j)
          acc[i][j] = __builtin_amdgcn_mfma_f32_16x16x32_bf16(bfr[j], af[i], acc[i][j], 0, 0, 0);
      if (wm == 0) {   // V-slice MFMA: D[s][n] for 12 sum-rows
        bf16x8 afx = *(const bf16x8*)(xsb + xrow*520 + kt + ks*32 + g4*8);
        #pragma unroll
        for (int j = 0; j < 4; ++j)
          accV[j] = __builtin_amdgcn_mfma_f32_16x16x32_bf16(afx, bfr[j], accV[j], 0, 0, 0);
      }
    }
    __builtin_amdgcn_sched_barrier(0);
    __builtin_amdgcn_s_barrier();
    __builtin_amdgcn_sched_barrier(0);
  }
#undef STAGE_T

  // Vl[12][128] f32 at SM+0 (As0 region dead)
  float* Vl = (float*)SM;
  if (wm == 0) {
    #pragma unroll
    for (int j = 0; j < 4; ++j) {
      const int c = wn*64 + j*16 + lr;
      const float bv = bias[n0 + c];
      #pragma unroll
      for (int r = 0; r < 4; ++r) {
        const int s = g4*4 + r;
        if (s < 12) Vl[s*128 + c] = accV[j][r] + (float)cnt[s] * bv;
      }
    }
  }
  __syncthreads();

  int fl[4]; float rdg[4]; bool cs[4];
  const float* Vb[4];   // per-i class-row base into Vl (LDS pointer, static offsets below)
  #pragma unroll
  for (int i = 0; i < 4; ++i) {
    const int m = m0 + wm*64 + i*16 + lr;
    const int f = rowfl[m];
    fl[i] = f;
    const int cls = f & 3;
    const int bD = (f >> 2) & 1, bA = (f >> 3) & 1, bZ = (f >> 4) & 1;
    const int rb = 3 + cls*3;
    const int c3c = bD*cnt[0] + bA*cnt[1] + bZ*cnt[2];
    const int c2c = cnt[rb] + cnt[rb+1] + cnt[rb+2] - bD*cnt[rb] - bA*cnt[rb+1] - bZ*cnt[rb+2];
    cs[i] = (cls == 0 && bD) || (cls == 1 && bA) || (cls == 2 && bZ);
    float deg = (float)(c3c + c2c) + (cs[i] ? 0.f : 1.f);
    if (deg < 1.f) deg = 1.f;
    rdg[i] = 1.f / deg;
    Vb[i] = Vl + rb*128;
  }

  if (MODE == 0) {
    u16* G = (u16*)outp;
    float* cbin = (float*)(SM + 8192);   // [2][2][4][16][3] = 768 f32 (dead region after Vl's 6KB)
    #pragma unroll
    for (int j = 0; j < 4; ++j) {
      const int dgb = n0 + wn*64 + j*16 + g4*4;
      u16x4 o[4];
      #pragma unroll
      for (int r = 0; r < 4; ++r) {
        const int c = wn*64 + j*16 + g4*4 + r;
        const float bv = bias[dgb + r];
        const float v0 = Vl[c], v1 = Vl[128 + c], v2 = Vl[256 + c];
        float s0 = 0.f, s1 = 0.f, s2 = 0.f;
        #pragma unroll
        for (int i = 0; i < 4; ++i) {
          const int f = fl[i];
          const float t0 = Vb[i][c], t1 = Vb[i][128 + c], t2 = Vb[i][256 + c];
          float c3 = ((f&4)?v0:0.f) + ((f&8)?v1:0.f) + ((f&16)?v2:0.f);
          float c2 = t0 + t1 + t2
                   - ((f&4)?t0:0.f) - ((f&8)?t1:0.f) - ((f&16)?t2:0.f);
          float val = (c3 + c2) * rdg[i];
          if (!cs[i]) val += (acc[i][j][r] + bv) * rdg[i];
          val = fmaxf(val, 0.f);
          o[i][r] = f2b(val);
          const int cls = f & 3;
          s0 += (cls == 0) ? val : 0.f;
          s1 += (cls == 1) ? val : 0.f;
          s2 += (cls == 2) ? val : 0.f;
          if (f & 0x1C) {  // rare: row in D/A/Z8 set -> sparse set-sum atomics
            if (f & 4)  atomicAdd(&osum[(size_t)(b*12 + 3 + cls)*512 + dgb + r], val);
            if (f & 8)  atomicAdd(&osum[(size_t)(b*12 + 6 + cls)*512 + dgb + r], val);
            if (f & 16) atomicAdd(&osum[(size_t)(b*12 + 9 + cls)*512 + dgb + r], val);
          }
        }
        // butterfly over the 16-lane group (same column c across the group)
        #pragma unroll
        for (int o2 = 1; o2 < 16; o2 <<= 1) {
          s0 += __shfl_xor(s0, o2, 64);
          s1 += __shfl_xor(s1, o2, 64);
          s2 += __shfl_xor(s2, o2, 64);
        }
        if (lr == 0) {
          float* cb = cbin + (((wm*2 + wn)*4 + g4)*16 + (j*4 + r))*3;
          cb[0] = s0; cb[1] = s1; cb[2] = s2;
        }
      }
      #pragma unroll
      for (int i = 0; i < 4; ++i)
        *(u16x4*)(G + (size_t)(m0 + wm*64 + i*16 + lr)*512 + dgb) = o[i];
    }
    __syncthreads();
    // combine wm halves; one global atomic per (wn,g4,jr,cls): 384 items on 256 threads (strided)
    for (int item = tid; item < 384; item += 256) {
      const int wg = item / 48;        // 0..7 = wn*4 + g4
      const int rem = item % 48;
      const int jr = rem / 3, cls = rem % 3;
      const int wnn = wg >> 2, gg = wg & 3;
      const int c = wnn*64 + (jr >> 2)*16 + gg*4 + (jr & 3);
      const float vsum = cbin[(((0*2 + wnn)*4 + gg)*16 + jr)*3 + cls]
                       + cbin[(((1*2 + wnn)*4 + gg)*16 + jr)*3 + cls];
      atomicAdd(&osum[(size_t)(b*12 + cls)*512 + n0 + c], vsum);
    }
  } else {
    float* out = (float*)outp;
    float (*ep)[130] = (float(*)[130])(SM + 8192);   // 32 rows x 130 f32 = 16640 B (dead As0/Bs0 region)
    const int nloc = m0 & 2047;
    for (int j = 0; j < 4; ++j) {
      #pragma unroll
      for (int r = 0; r < 4; ++r) {
        const int c = wn*64 + j*16 + g4*4 + r;
        const float bv = bias[n0 + c];
        const float v0 = Vl[c], v1 = Vl[128 + c], v2 = Vl[256 + c];
        #pragma unroll
        for (int i = 0; i < 4; ++i) {
          const int f = fl[i];
          const float t0 = Vb[i][c], t1 = Vb[i][128 + c], t2 = Vb[i][256 + c];
          float c3 = ((f&4)?v0:0.f) + ((f&8)?v1:0.f) + ((f&16)?v2:0.f);
          float c2 = t0 + t1 + t2
                   - ((f&4)?t0:0.f) - ((f&8)?t1:0.f) - ((f&16)?t2:0.f);
          float val = (c3 + c2) * rdg[i];
          if (!cs[i]) val += (acc[i][j][r] + bv) * rdg[i];
          ep[wn*16 + g4*4 + r][wm*64 + i*16 + lr] = val;
        }
      }
      __syncthreads();
      // drain all 32 ep rows: 4 waves x 8 rows x (64 lanes x f32x2 = 128 m)
      #pragma unroll
      for (int rr = 0; rr < 8; ++rr) {
        const int q = w*8 + rr;
        const int s = n0 + (q >> 4)*64 + j*16 + (q & 15);
        float2 v2 = *(const float2*)&ep[q][2*l];
        *(float2*)(out + ((size_t)b*SS + s)*NN + nloc + 2*l) = v2;
      }
      __syncthreads();
    }
  }
}

extern "C" void kernel_launch(void* const* d_in, const int* in_sizes, int n_in,
                              void* d_out, int out_size, void* d_ws, size_t ws_size,
                              hipStream_t stream) {
  const float* x  = (const float*)d_in[0];
  const float* W1 = (const float*)d_in[1];
  const float* b1 = (const float*)d_in[2];
  const float* W2 = (const float*)d_in[3];
  const float* b2 = (const float*)d_in[4];
  float* out = (float*)d_out;
  char* ws = (char*)d_ws;

  float* fvp   = (float*)(ws + 0);           // 512 KB (8*8*2048 f32)
  int*   meta  = (int*)  (ws + 1048576);     // 1 KB
  int*   rowfl = (int*)  (ws + 1049600);     // 64 KB
  float* xs    = (float*)(ws + 1115136);     // 192 KB  [b][12][512] f32
  float* g1s   = (float*)(ws + 1311744);     // 192 KB  (contiguous after xs for zeroing)
  u16*   w1b   = (u16*)  (ws + 1508352);     // 512 KB
  u16*   w2b   = (u16*)  (ws + 2032640);     // 512 KB
  u16*   g1    = (u16*)  (ws + 2556928);     // 16 MB
  u16*   xr    = (u16*)  (ws + 19334144);    // 16 MB

  k_prep<<<4608, 256, 0, stream>>>(x, xr, fvp, W1, W2, w1b, w2b, xs);
  k_tops<<<264, 256, 0, stream>>>(fvp, xr, meta, rowfl, xs);
  k_gemmf<0><<<512, 256, 0, stream>>>(xr, w1b, b1, xs, meta, rowfl, (void*)g1, g1s);
  k_gemmf<1><<<512, 256, 0, stream>>>(g1, w2b, b2, g1s, meta, rowfl, (void*)out, nullptr);
}